// Round 2
// baseline (185.612 us; speedup 1.0000x reference)
//
#include <hip/hip_runtime.h>
#include <cstdint>
#include <cstddef>

#define HDIM 512
#define NM 32
#define NBATCH 4096

// ---------------- Threefry-2x32-20, key = (0,1)  (jax.random.key(1)) -------
__device__ __forceinline__ unsigned rotl32(unsigned x, unsigned d) {
  return (x << d) | (x >> (32u - d));
}

__device__ __forceinline__ void threefry2x32(unsigned& x0, unsigned& x1) {
  const unsigned ks0 = 0u, ks1 = 1u, ks2 = 0x1BD11BDBu; // 0^1^0x1BD11BDA
  x0 += ks0; x1 += ks1;
#define TF_RND(r) { x0 += x1; x1 = rotl32(x1, (r)); x1 ^= x0; }
  TF_RND(13) TF_RND(15) TF_RND(26) TF_RND(6)
  x0 += ks1; x1 += ks2 + 1u;
  TF_RND(17) TF_RND(29) TF_RND(16) TF_RND(24)
  x0 += ks2; x1 += ks0 + 2u;
  TF_RND(13) TF_RND(15) TF_RND(26) TF_RND(6)
  x0 += ks0; x1 += ks1 + 3u;
  TF_RND(17) TF_RND(29) TF_RND(16) TF_RND(24)
  x0 += ks1; x1 += ks2 + 4u;
  TF_RND(13) TF_RND(15) TF_RND(26) TF_RND(6)
  x0 += ks2; x1 += ks0 + 5u;
#undef TF_RND
}

// ---------------- Hc[b,:] = h_s[cur[b],:] + h_d[cur[b],:] ------------------
__global__ void gather_hc(const float* __restrict__ hs,
                          const float* __restrict__ hd,
                          const int* __restrict__ cur,
                          float* __restrict__ Hc) {
  const int b = blockIdx.x;
  const int t = threadIdx.x;             // 128 threads, float4 each -> 512 f
  const int n = cur[b];
  const float4 a = ((const float4*)(hs + (size_t)n * HDIM))[t];
  const float4 c = ((const float4*)(hd + (size_t)n * HDIM))[t];
  float4 r;
  r.x = a.x + c.x; r.y = a.y + c.y; r.z = a.z + c.z; r.w = a.w + c.w;
  ((float4*)(Hc + (size_t)b * HDIM))[t] = r;
}

// ---------------- M2T[c,e] = dot(W*_kvl[c, 0:512], Wq[e, 0:512]) -----------
// c in [0,1024): c<512 -> Ws_kvl row c, else Wd_kvl row c-512 (lda=1536).
// NT gemm, 64x64 tile, 4x4 micro, transposed LDS.
__global__ __launch_bounds__(256) void gemm_b1(const float* __restrict__ Ws,
                                               const float* __restrict__ Wd,
                                               const float* __restrict__ Wq,
                                               float* __restrict__ M2T) {
  constexpr int BK = 16, LDT = 68;  // 64 + 4 pad
  __shared__ float Ast[BK][LDT];
  __shared__ float Bst[BK][LDT];
  const int tid = threadIdx.x;
  const int row0 = blockIdx.y * 64;      // combined c row
  const int col0 = blockIdx.x * 64;      // e
  const float* Abase = (row0 < 512) ? Ws : Wd;
  const int arow0 = (row0 < 512) ? row0 : row0 - 512;
  const int tx = tid & 15, ty = tid >> 4;
  const int lr = tid >> 2, lc = (tid & 3) * 4;
  float acc[4][4] = {};
  for (int k0 = 0; k0 < 512; k0 += BK) {
    float4 va = *(const float4*)(Abase + (size_t)(arow0 + lr) * 1536 + k0 + lc);
    float4 vb = *(const float4*)(Wq + (size_t)(col0 + lr) * 512 + k0 + lc);
    Ast[lc + 0][lr] = va.x; Ast[lc + 1][lr] = va.y;
    Ast[lc + 2][lr] = va.z; Ast[lc + 3][lr] = va.w;
    Bst[lc + 0][lr] = vb.x; Bst[lc + 1][lr] = vb.y;
    Bst[lc + 2][lr] = vb.z; Bst[lc + 3][lr] = vb.w;
    __syncthreads();
#pragma unroll
    for (int k = 0; k < BK; ++k) {
      float4 a4 = *(const float4*)&Ast[k][ty * 4];
      float4 b4 = *(const float4*)&Bst[k][tx * 4];
      float a[4] = {a4.x, a4.y, a4.z, a4.w};
      float bb[4] = {b4.x, b4.y, b4.z, b4.w};
#pragma unroll
      for (int i = 0; i < 4; ++i)
#pragma unroll
        for (int j = 0; j < 4; ++j) acc[i][j] += a[i] * bb[j];
    }
    __syncthreads();
  }
#pragma unroll
  for (int i = 0; i < 4; ++i) {
    float4 o;
    o.x = acc[i][0]; o.y = acc[i][1]; o.z = acc[i][2]; o.w = acc[i][3];
    *(float4*)(M2T + (size_t)(row0 + ty * 4 + i) * 512 + col0 + tx * 4) = o;
  }
}

// ---------------- V[b,c] = dot(Hc[b,:], M2T[c,:])  (4096x1024, K=512) ------
// 128x128 tile, 8x8 micro, transposed+padded LDS -> ds_read_b128 inner loop.
__global__ __launch_bounds__(256) void gemm_v(const float* __restrict__ A,
                                              const float* __restrict__ Bm,
                                              float* __restrict__ C) {
  constexpr int BK = 16, LDT = 132;  // 128 + 4 pad
  __shared__ float Ast[BK][LDT];
  __shared__ float Bst[BK][LDT];
  const int tid = threadIdx.x;
  const int row0 = blockIdx.y * 128;
  const int col0 = blockIdx.x * 128;
  const int tx = tid & 15, ty = tid >> 4;
  const int lr = tid >> 2, lc = (tid & 3) * 4;
  float acc[8][8] = {};
  for (int k0 = 0; k0 < 512; k0 += BK) {
#pragma unroll
    for (int h = 0; h < 2; ++h) {
      const int r = lr + h * 64;
      float4 va = *(const float4*)(A + (size_t)(row0 + r) * 512 + k0 + lc);
      float4 vb = *(const float4*)(Bm + (size_t)(col0 + r) * 512 + k0 + lc);
      Ast[lc + 0][r] = va.x; Ast[lc + 1][r] = va.y;
      Ast[lc + 2][r] = va.z; Ast[lc + 3][r] = va.w;
      Bst[lc + 0][r] = vb.x; Bst[lc + 1][r] = vb.y;
      Bst[lc + 2][r] = vb.z; Bst[lc + 3][r] = vb.w;
    }
    __syncthreads();
#pragma unroll
    for (int k = 0; k < BK; ++k) {
      float4 a0 = *(const float4*)&Ast[k][ty * 8];
      float4 a1 = *(const float4*)&Ast[k][ty * 8 + 4];
      float4 b0 = *(const float4*)&Bst[k][tx * 8];
      float4 b1 = *(const float4*)&Bst[k][tx * 8 + 4];
      float a[8] = {a0.x, a0.y, a0.z, a0.w, a1.x, a1.y, a1.z, a1.w};
      float bb[8] = {b0.x, b0.y, b0.z, b0.w, b1.x, b1.y, b1.z, b1.w};
#pragma unroll
      for (int i = 0; i < 8; ++i)
#pragma unroll
        for (int j = 0; j < 8; ++j) acc[i][j] += a[i] * bb[j];
    }
    __syncthreads();
  }
#pragma unroll
  for (int i = 0; i < 8; ++i) {
    float4 o0, o1;
    o0.x = acc[i][0]; o0.y = acc[i][1]; o0.z = acc[i][2]; o0.w = acc[i][3];
    o1.x = acc[i][4]; o1.y = acc[i][5]; o1.z = acc[i][6]; o1.w = acc[i][7];
    float* cp = C + (size_t)(row0 + ty * 8 + i) * 1024 + col0 + tx * 8;
    *(float4*)cp = o0;
    *(float4*)(cp + 4) = o1;
  }
}

// ---------------- per-b: compat, Gumbel argmax, log-softmax ----------------
__global__ __launch_bounds__(256) void attend_kernel(
    const float* __restrict__ hs, const float* __restrict__ hd,
    const float* __restrict__ V, const int* __restrict__ neigh,
    const int* __restrict__ lengths, const int* __restrict__ cur,
    float* __restrict__ out) {
  const int b = blockIdx.x;
  const int tid = threadIdx.x;
  const int lane = tid & 63;
  const int wave = tid >> 6;
  __shared__ float compat[NM];

  // each lane owns h-slice [lane*8, lane*8+8); V row is reused across all m
  const float4* vrow = (const float4*)(V + (size_t)b * (2 * HDIM));
  const float4 w0 = vrow[lane * 2], w1 = vrow[lane * 2 + 1];          // Vs
  const float4 u0 = vrow[128 + lane * 2], u1 = vrow[128 + lane * 2 + 1];  // Vd

#pragma unroll
  for (int mi = 0; mi < 8; ++mi) {
    const int m = wave * 8 + mi;
    const int n = neigh[b * NM + m];
    const float4* a4 = (const float4*)(hs + (size_t)n * HDIM);
    const float4* c4 = (const float4*)(hd + (size_t)n * HDIM);
    const float4 a0 = a4[lane * 2], a1 = a4[lane * 2 + 1];
    const float4 b0 = c4[lane * 2], b1 = c4[lane * 2 + 1];
    float acc = a0.x * w0.x + a0.y * w0.y + a0.z * w0.z + a0.w * w0.w
              + a1.x * w1.x + a1.y * w1.y + a1.z * w1.z + a1.w * w1.w
              + b0.x * u0.x + b0.y * u0.y + b0.z * u0.z + b0.w * u0.w
              + b1.x * u1.x + b1.y * u1.y + b1.z * u1.z + b1.w * u1.w;
#pragma unroll
    for (int off = 32; off >= 1; off >>= 1) acc += __shfl_xor(acc, off);
    if (lane == 0) compat[m] = acc;
  }
  __syncthreads();

  if (tid < 64) {
    const int len = lengths[b];
    const bool valid = tid < NM;
    const float NEGMAX = -3.402823466e38f;
    float logit = NEGMAX;
    if (valid) {
      const float cm = compat[tid] / 22.62741699796952f;  // / sqrt(512)
      logit = (tid < len) ? cm : -1e9f;
    }
    float z = NEGMAX;
    int zi = 1 << 20;
    if (valid) {
      // JAX partitionable threefry (default since 0.4.36):
      // counter = 64-bit flat index i -> threefry2x32(key, (i>>32, i&0xffffffff)),
      // 32-bit draw = out0 ^ out1.
      const unsigned i_lo = (unsigned)b * 32u + (unsigned)tid;
      unsigned x0 = 0u;      // i >> 32 == 0 for B*M = 131072
      unsigned x1 = i_lo;
      threefry2x32(x0, x1);
      const unsigned bits = x0 ^ x1;
      const float fu = __uint_as_float((bits >> 9) | 0x3f800000u) - 1.0f;
      const float uu = fmaxf(1e-8f, fu + 1e-8f);  // (maxval-minval) rounds to 1.0f
      const float g = -logf(-logf(uu));
      z = logit + g;
      zi = tid;
    }
    // argmax with first-index tie-break
#pragma unroll
    for (int off = 32; off >= 1; off >>= 1) {
      const float oz = __shfl_xor(z, off);
      const int oi = __shfl_xor(zi, off);
      if (oz > z || (oz == z && oi < zi)) { z = oz; zi = oi; }
    }
    float ml = logit;
#pragma unroll
    for (int off = 32; off >= 1; off >>= 1) ml = fmaxf(ml, __shfl_xor(ml, off));
    float ex = valid ? expf(logit - ml) : 0.f;
#pragma unroll
    for (int off = 32; off >= 1; off >>= 1) ex += __shfl_xor(ex, off);
    const float lsel = __shfl(logit, zi);
    if (tid == 0) {
      float lp = lsel - ml - logf(ex);
      int act = neigh[b * NM + zi];
      if (len <= 0) { act = cur[b]; lp = 0.f; }
      out[b] = (float)act;
      out[NBATCH + b] = lp;
    }
  }
}

extern "C" void kernel_launch(void* const* d_in, const int* in_sizes, int n_in,
                              void* d_out, int out_size, void* d_ws, size_t ws_size,
                              hipStream_t stream) {
  const float* hs = (const float*)d_in[0];
  const float* hd = (const float*)d_in[1];
  const float* Ws = (const float*)d_in[2];
  const float* Wd = (const float*)d_in[3];
  const float* Wq = (const float*)d_in[4];
  const int* cur = (const int*)d_in[6];
  const int* neigh = (const int*)d_in[7];
  const int* lens = (const int*)d_in[8];
  float* out = (float*)d_out;

  char* ws = (char*)d_ws;
  float* Hc  = (float*)ws;                                   // 4096x512   (8 MB)
  float* M2T = (float*)(ws + (size_t)NBATCH * HDIM * 4);     // 1024x512   (2 MB)
  float* V   = (float*)(ws + (size_t)NBATCH * HDIM * 4 + (size_t)1024 * 512 * 4);  // 4096x1024 (16 MB)

  hipLaunchKernelGGL(gemm_b1, dim3(8, 16), dim3(256), 0, stream, Ws, Wd, Wq, M2T);
  hipLaunchKernelGGL(gather_hc, dim3(NBATCH), dim3(128), 0, stream, hs, hd, cur, Hc);
  hipLaunchKernelGGL(gemm_v, dim3(8, 32), dim3(256), 0, stream, Hc, M2T, V);
  hipLaunchKernelGGL(attend_kernel, dim3(NBATCH), dim3(256), 0, stream,
                     hs, hd, V, neigh, lens, cur, out);
}

// Round 3
// 177.921 us; speedup vs baseline: 1.0432x; 1.0432x over previous
//
#include <hip/hip_runtime.h>
#include <cstdint>
#include <cstddef>

#define HDIM 512
#define NM 32
#define NBATCH 4096
#define NNODE 65536
#define CAP 16

// ---------------- Threefry-2x32-20, key = (0,1)  (jax.random.key(1)) -------
__device__ __forceinline__ unsigned rotl32(unsigned x, unsigned d) {
  return (x << d) | (x >> (32u - d));
}

__device__ __forceinline__ void threefry2x32(unsigned& x0, unsigned& x1) {
  const unsigned ks0 = 0u, ks1 = 1u, ks2 = 0x1BD11BDBu; // 0^1^0x1BD11BDA
  x0 += ks0; x1 += ks1;
#define TF_RND(r) { x0 += x1; x1 = rotl32(x1, (r)); x1 ^= x0; }
  TF_RND(13) TF_RND(15) TF_RND(26) TF_RND(6)
  x0 += ks1; x1 += ks2 + 1u;
  TF_RND(17) TF_RND(29) TF_RND(16) TF_RND(24)
  x0 += ks2; x1 += ks0 + 2u;
  TF_RND(13) TF_RND(15) TF_RND(26) TF_RND(6)
  x0 += ks0; x1 += ks1 + 3u;
  TF_RND(17) TF_RND(29) TF_RND(16) TF_RND(24)
  x0 += ks1; x1 += ks2 + 4u;
  TF_RND(13) TF_RND(15) TF_RND(26) TF_RND(6)
  x0 += ks2; x1 += ks0 + 5u;
#undef TF_RND
}

// ---------------- Hc[b,:] = h_s[cur[b],:] + h_d[cur[b],:] ------------------
__global__ void gather_hc(const float* __restrict__ hs,
                          const float* __restrict__ hd,
                          const int* __restrict__ cur,
                          float* __restrict__ Hc) {
  const int b = blockIdx.x;
  const int t = threadIdx.x;             // 128 threads, float4 each -> 512 f
  const int n = cur[b];
  const float4 a = ((const float4*)(hs + (size_t)n * HDIM))[t];
  const float4 c = ((const float4*)(hd + (size_t)n * HDIM))[t];
  float4 r;
  r.x = a.x + c.x; r.y = a.y + c.y; r.z = a.z + c.z; r.w = a.w + c.w;
  ((float4*)(Hc + (size_t)b * HDIM))[t] = r;
}

// ---------------- M2T[c,e] = dot(W*_kvl[c, 0:512], Wq[e, 0:512]) -----------
__global__ __launch_bounds__(256) void gemm_b1(const float* __restrict__ Ws,
                                               const float* __restrict__ Wd,
                                               const float* __restrict__ Wq,
                                               float* __restrict__ M2T) {
  constexpr int BK = 16, LDT = 68;  // 64 + 4 pad
  __shared__ float Ast[BK][LDT];
  __shared__ float Bst[BK][LDT];
  const int tid = threadIdx.x;
  const int row0 = blockIdx.y * 64;      // combined c row
  const int col0 = blockIdx.x * 64;      // e
  const float* Abase = (row0 < 512) ? Ws : Wd;
  const int arow0 = (row0 < 512) ? row0 : row0 - 512;
  const int tx = tid & 15, ty = tid >> 4;
  const int lr = tid >> 2, lc = (tid & 3) * 4;
  float acc[4][4] = {};
  for (int k0 = 0; k0 < 512; k0 += BK) {
    float4 va = *(const float4*)(Abase + (size_t)(arow0 + lr) * 1536 + k0 + lc);
    float4 vb = *(const float4*)(Wq + (size_t)(col0 + lr) * 512 + k0 + lc);
    Ast[lc + 0][lr] = va.x; Ast[lc + 1][lr] = va.y;
    Ast[lc + 2][lr] = va.z; Ast[lc + 3][lr] = va.w;
    Bst[lc + 0][lr] = vb.x; Bst[lc + 1][lr] = vb.y;
    Bst[lc + 2][lr] = vb.z; Bst[lc + 3][lr] = vb.w;
    __syncthreads();
#pragma unroll
    for (int k = 0; k < BK; ++k) {
      float4 a4 = *(const float4*)&Ast[k][ty * 4];
      float4 b4 = *(const float4*)&Bst[k][tx * 4];
      float a[4] = {a4.x, a4.y, a4.z, a4.w};
      float bb[4] = {b4.x, b4.y, b4.z, b4.w};
#pragma unroll
      for (int i = 0; i < 4; ++i)
#pragma unroll
        for (int j = 0; j < 4; ++j) acc[i][j] += a[i] * bb[j];
    }
    __syncthreads();
  }
#pragma unroll
  for (int i = 0; i < 4; ++i) {
    float4 o;
    o.x = acc[i][0]; o.y = acc[i][1]; o.z = acc[i][2]; o.w = acc[i][3];
    *(float4*)(M2T + (size_t)(row0 + ty * 4 + i) * 512 + col0 + tx * 4) = o;
  }
}

// ---------------- V[b,c] = dot(Hc[b,:], M2T[c,:])  (4096x1024, K=512) ------
__global__ __launch_bounds__(256) void gemm_v(const float* __restrict__ A,
                                              const float* __restrict__ Bm,
                                              float* __restrict__ C) {
  constexpr int BK = 16, LDT = 132;  // 128 + 4 pad
  __shared__ float Ast[BK][LDT];
  __shared__ float Bst[BK][LDT];
  const int tid = threadIdx.x;
  const int row0 = blockIdx.y * 128;
  const int col0 = blockIdx.x * 128;
  const int tx = tid & 15, ty = tid >> 4;
  const int lr = tid >> 2, lc = (tid & 3) * 4;
  float acc[8][8] = {};
  for (int k0 = 0; k0 < 512; k0 += BK) {
#pragma unroll
    for (int h = 0; h < 2; ++h) {
      const int r = lr + h * 64;
      float4 va = *(const float4*)(A + (size_t)(row0 + r) * 512 + k0 + lc);
      float4 vb = *(const float4*)(Bm + (size_t)(col0 + r) * 512 + k0 + lc);
      Ast[lc + 0][r] = va.x; Ast[lc + 1][r] = va.y;
      Ast[lc + 2][r] = va.z; Ast[lc + 3][r] = va.w;
      Bst[lc + 0][r] = vb.x; Bst[lc + 1][r] = vb.y;
      Bst[lc + 2][r] = vb.z; Bst[lc + 3][r] = vb.w;
    }
    __syncthreads();
#pragma unroll
    for (int k = 0; k < BK; ++k) {
      float4 a0 = *(const float4*)&Ast[k][ty * 8];
      float4 a1 = *(const float4*)&Ast[k][ty * 8 + 4];
      float4 b0 = *(const float4*)&Bst[k][tx * 8];
      float4 b1 = *(const float4*)&Bst[k][tx * 8 + 4];
      float a[8] = {a0.x, a0.y, a0.z, a0.w, a1.x, a1.y, a1.z, a1.w};
      float bb[8] = {b0.x, b0.y, b0.z, b0.w, b1.x, b1.y, b1.z, b1.w};
#pragma unroll
      for (int i = 0; i < 8; ++i)
#pragma unroll
        for (int j = 0; j < 8; ++j) acc[i][j] += a[i] * bb[j];
    }
    __syncthreads();
  }
#pragma unroll
  for (int i = 0; i < 8; ++i) {
    float4 o0, o1;
    o0.x = acc[i][0]; o0.y = acc[i][1]; o0.z = acc[i][2]; o0.w = acc[i][3];
    o1.x = acc[i][4]; o1.y = acc[i][5]; o1.z = acc[i][6]; o1.w = acc[i][7];
    float* cp = C + (size_t)(row0 + ty * 8 + i) * 1024 + col0 + tx * 8;
    *(float4*)cp = o0;
    *(float4*)(cp + 4) = o1;
  }
}

// ---------------- inverted index: node -> list of (b*32+m) -----------------
__global__ __launch_bounds__(256) void build_index(
    const int* __restrict__ neigh, const int* __restrict__ lens,
    int* __restrict__ cnt, int* __restrict__ bucket,
    int* __restrict__ ovf_cnt, int* __restrict__ ovf_list) {
  const int t = blockIdx.x * 256 + threadIdx.x;   // t in [0, B*M)
  const int b = t >> 5, m = t & 31;
  if (m < lens[b]) {
    const int n = neigh[t];
    const int slot = atomicAdd(&cnt[n], 1);
    if (slot < CAP) bucket[n * CAP + slot] = t;
    else { const int o = atomicAdd(ovf_cnt, 1); ovf_list[o] = t; }
  }
}

// ---------------- streaming compat: one wave per node ----------------------
// Reads hs/hd sequentially (only nodes with refs), dots against V[b] per ref.
// Arithmetic order identical to the verified gather kernel.
__global__ __launch_bounds__(256) void stream_compat(
    const float* __restrict__ hs, const float* __restrict__ hd,
    const float* __restrict__ V, const int* __restrict__ cnt,
    const int* __restrict__ bucket, float* __restrict__ compat) {
  const int n = blockIdx.x * 4 + (threadIdx.x >> 6);   // node per wave
  const int lane = threadIdx.x & 63;
  const int c = cnt[n];
  if (c == 0) return;
  const float4* a4 = (const float4*)(hs + (size_t)n * HDIM);
  const float4* c4 = (const float4*)(hd + (size_t)n * HDIM);
  const float4 a0 = a4[lane * 2], a1 = a4[lane * 2 + 1];
  const float4 b0 = c4[lane * 2], b1 = c4[lane * 2 + 1];
  const int cc = (c < CAP) ? c : CAP;
  for (int e = 0; e < cc; ++e) {
    const int t = bucket[n * CAP + e];
    const int b = t >> 5;
    const float4* vrow = (const float4*)(V + (size_t)b * (2 * HDIM));
    const float4 w0 = vrow[lane * 2], w1 = vrow[lane * 2 + 1];
    const float4 u0 = vrow[128 + lane * 2], u1 = vrow[128 + lane * 2 + 1];
    float acc = a0.x * w0.x + a0.y * w0.y + a0.z * w0.z + a0.w * w0.w
              + a1.x * w1.x + a1.y * w1.y + a1.z * w1.z + a1.w * w1.w
              + b0.x * u0.x + b0.y * u0.y + b0.z * u0.z + b0.w * u0.w
              + b1.x * u1.x + b1.y * u1.y + b1.z * u1.z + b1.w * u1.w;
#pragma unroll
    for (int off = 32; off >= 1; off >>= 1) acc += __shfl_xor(acc, off);
    if (lane == 0) compat[t] = acc;
  }
}

// ---------------- overflow path (virtually never executes) -----------------
__global__ __launch_bounds__(256) void ovf_compat(
    const float* __restrict__ hs, const float* __restrict__ hd,
    const float* __restrict__ V, const int* __restrict__ ovf_cnt,
    const int* __restrict__ ovf_list, const int* __restrict__ neigh,
    float* __restrict__ compat) {
  const int nw = *ovf_cnt;
  const int lane = threadIdx.x & 63;
  for (int e = blockIdx.x * 4 + (threadIdx.x >> 6); e < nw; e += gridDim.x * 4) {
    const int t = ovf_list[e];
    const int b = t >> 5;
    const int n = neigh[t];
    const float4* a4 = (const float4*)(hs + (size_t)n * HDIM);
    const float4* c4 = (const float4*)(hd + (size_t)n * HDIM);
    const float4 a0 = a4[lane * 2], a1 = a4[lane * 2 + 1];
    const float4 b0 = c4[lane * 2], b1 = c4[lane * 2 + 1];
    const float4* vrow = (const float4*)(V + (size_t)b * (2 * HDIM));
    const float4 w0 = vrow[lane * 2], w1 = vrow[lane * 2 + 1];
    const float4 u0 = vrow[128 + lane * 2], u1 = vrow[128 + lane * 2 + 1];
    float acc = a0.x * w0.x + a0.y * w0.y + a0.z * w0.z + a0.w * w0.w
              + a1.x * w1.x + a1.y * w1.y + a1.z * w1.z + a1.w * w1.w
              + b0.x * u0.x + b0.y * u0.y + b0.z * u0.z + b0.w * u0.w
              + b1.x * u1.x + b1.y * u1.y + b1.z * u1.z + b1.w * u1.w;
#pragma unroll
    for (int off = 32; off >= 1; off >>= 1) acc += __shfl_xor(acc, off);
    if (lane == 0) compat[t] = acc;
  }
}

// ---------------- per-b: Gumbel argmax + log-softmax (one wave per b) ------
__global__ __launch_bounds__(256) void finalize_kernel(
    const float* __restrict__ compat, const int* __restrict__ neigh,
    const int* __restrict__ lengths, const int* __restrict__ cur,
    float* __restrict__ out) {
  const int b = blockIdx.x * 4 + (threadIdx.x >> 6);
  const int tid = threadIdx.x & 63;
  const int len = lengths[b];
  const bool valid = tid < NM;
  const float NEGMAX = -3.402823466e38f;
  float logit = NEGMAX;
  if (valid) {
    const float cm = compat[b * NM + tid] / 22.62741699796952f;  // / sqrt(512)
    logit = (tid < len) ? cm : -1e9f;
  }
  float z = NEGMAX;
  int zi = 1 << 20;
  if (valid) {
    // JAX partitionable threefry: counter = 64-bit flat index,
    // draw = out0 ^ out1 of threefry2x32(key=(0,1), (hi, lo)).
    const unsigned i_lo = (unsigned)b * 32u + (unsigned)tid;
    unsigned x0 = 0u;
    unsigned x1 = i_lo;
    threefry2x32(x0, x1);
    const unsigned bits = x0 ^ x1;
    const float fu = __uint_as_float((bits >> 9) | 0x3f800000u) - 1.0f;
    const float uu = fmaxf(1e-8f, fu + 1e-8f);
    const float g = -logf(-logf(uu));
    z = logit + g;
    zi = tid;
  }
#pragma unroll
  for (int off = 32; off >= 1; off >>= 1) {
    const float oz = __shfl_xor(z, off);
    const int oi = __shfl_xor(zi, off);
    if (oz > z || (oz == z && oi < zi)) { z = oz; zi = oi; }
  }
  float ml = logit;
#pragma unroll
  for (int off = 32; off >= 1; off >>= 1) ml = fmaxf(ml, __shfl_xor(ml, off));
  float ex = valid ? expf(logit - ml) : 0.f;
#pragma unroll
  for (int off = 32; off >= 1; off >>= 1) ex += __shfl_xor(ex, off);
  const float lsel = __shfl(logit, zi);
  if (tid == 0) {
    float lp = lsel - ml - logf(ex);
    int act = neigh[b * NM + zi];
    if (len <= 0) { act = cur[b]; lp = 0.f; }
    out[b] = (float)act;
    out[NBATCH + b] = lp;
  }
}

extern "C" void kernel_launch(void* const* d_in, const int* in_sizes, int n_in,
                              void* d_out, int out_size, void* d_ws, size_t ws_size,
                              hipStream_t stream) {
  const float* hs = (const float*)d_in[0];
  const float* hd = (const float*)d_in[1];
  const float* Ws = (const float*)d_in[2];
  const float* Wd = (const float*)d_in[3];
  const float* Wq = (const float*)d_in[4];
  const int* cur = (const int*)d_in[6];
  const int* neigh = (const int*)d_in[7];
  const int* lens = (const int*)d_in[8];
  float* out = (float*)d_out;

  char* ws = (char*)d_ws;
  size_t off = 0;
  int* cnt = (int*)(ws + off);        off += (size_t)NNODE * 4;        // 256 KB
  int* ovf_cnt = (int*)(ws + off);    off += 256;                      // pad
  int* bucket = (int*)(ws + off);     off += (size_t)NNODE * CAP * 4;  // 4 MB
  int* ovf_list = (int*)(ws + off);   off += (size_t)NBATCH * NM * 4;  // 512 KB
  float* compat = (float*)(ws + off); off += (size_t)NBATCH * NM * 4;  // 512 KB
  float* Hc = (float*)(ws + off);     off += (size_t)NBATCH * HDIM * 4;    // 8 MB
  float* M2T = (float*)(ws + off);    off += (size_t)1024 * 512 * 4;       // 2 MB
  float* V = (float*)(ws + off);      off += (size_t)NBATCH * 2 * HDIM * 4; // 16 MB

  hipMemsetAsync(cnt, 0, (size_t)NNODE * 4 + 256, stream);
  hipLaunchKernelGGL(build_index, dim3(NBATCH * NM / 256), dim3(256), 0, stream,
                     neigh, lens, cnt, bucket, ovf_cnt, ovf_list);
  hipLaunchKernelGGL(gemm_b1, dim3(8, 16), dim3(256), 0, stream, Ws, Wd, Wq, M2T);
  hipLaunchKernelGGL(gather_hc, dim3(NBATCH), dim3(128), 0, stream, hs, hd, cur, Hc);
  hipLaunchKernelGGL(gemm_v, dim3(8, 32), dim3(256), 0, stream, Hc, M2T, V);
  hipLaunchKernelGGL(stream_compat, dim3(NNODE / 4), dim3(256), 0, stream,
                     hs, hd, V, cnt, bucket, compat);
  hipLaunchKernelGGL(ovf_compat, dim3(32), dim3(256), 0, stream,
                     hs, hd, V, ovf_cnt, ovf_list, neigh, compat);
  hipLaunchKernelGGL(finalize_kernel, dim3(NBATCH / 4), dim3(256), 0, stream,
                     compat, neigh, lens, cur, out);
}

// Round 5
// 174.464 us; speedup vs baseline: 1.0639x; 1.0198x over previous
//
#include <hip/hip_runtime.h>
#include <cstdint>
#include <cstddef>

#define HDIM 512
#define NM 32
#define NBATCH 4096
#define NNODE 65536
#define CAP 16

// ---------------- Threefry-2x32-20, key = (0,1)  (jax.random.key(1)) -------
__device__ __forceinline__ unsigned rotl32(unsigned x, unsigned d) {
  return (x << d) | (x >> (32u - d));
}

__device__ __forceinline__ void threefry2x32(unsigned& x0, unsigned& x1) {
  const unsigned ks0 = 0u, ks1 = 1u, ks2 = 0x1BD11BDBu; // 0^1^0x1BD11BDA
  x0 += ks0; x1 += ks1;
#define TF_RND(r) { x0 += x1; x1 = rotl32(x1, (r)); x1 ^= x0; }
  TF_RND(13) TF_RND(15) TF_RND(26) TF_RND(6)
  x0 += ks1; x1 += ks2 + 1u;
  TF_RND(17) TF_RND(29) TF_RND(16) TF_RND(24)
  x0 += ks2; x1 += ks0 + 2u;
  TF_RND(13) TF_RND(15) TF_RND(26) TF_RND(6)
  x0 += ks0; x1 += ks1 + 3u;
  TF_RND(17) TF_RND(29) TF_RND(16) TF_RND(24)
  x0 += ks1; x1 += ks2 + 4u;
  TF_RND(13) TF_RND(15) TF_RND(26) TF_RND(6)
  x0 += ks2; x1 += ks0 + 5u;
#undef TF_RND
}

// ---------------- zero cnt + ovf_cnt (replaces hipMemsetAsync) -------------
__global__ __launch_bounds__(256) void zero_cnt(int* __restrict__ cnt,
                                                int* __restrict__ ovf_cnt) {
  const int t = blockIdx.x * 256 + threadIdx.x;   // 64 blocks -> 16384 int4
  ((int4*)cnt)[t] = make_int4(0, 0, 0, 0);
  if (t == 0) *ovf_cnt = 0;
}

// ---------------- Hc[b,:] = h_s[cur[b],:] + h_d[cur[b],:] ------------------
__global__ void gather_hc(const float* __restrict__ hs,
                          const float* __restrict__ hd,
                          const int* __restrict__ cur,
                          float* __restrict__ Hc) {
  const int b = blockIdx.x;
  const int t = threadIdx.x;             // 128 threads, float4 each -> 512 f
  const int n = cur[b];
  const float4 a = ((const float4*)(hs + (size_t)n * HDIM))[t];
  const float4 c = ((const float4*)(hd + (size_t)n * HDIM))[t];
  float4 r;
  r.x = a.x + c.x; r.y = a.y + c.y; r.z = a.z + c.z; r.w = a.w + c.w;
  ((float4*)(Hc + (size_t)b * HDIM))[t] = r;
}

// ---------------- M2T[c,e] = dot(W*_kvl[c, 0:512], Wq[e, 0:512]) -----------
__global__ __launch_bounds__(256) void gemm_b1(const float* __restrict__ Ws,
                                               const float* __restrict__ Wd,
                                               const float* __restrict__ Wq,
                                               float* __restrict__ M2T) {
  constexpr int BK = 16, LDT = 68;  // 64 + 4 pad
  __shared__ float Ast[BK][LDT];
  __shared__ float Bst[BK][LDT];
  const int tid = threadIdx.x;
  const int row0 = blockIdx.y * 64;      // combined c row
  const int col0 = blockIdx.x * 64;      // e
  const float* Abase = (row0 < 512) ? Ws : Wd;
  const int arow0 = (row0 < 512) ? row0 : row0 - 512;
  const int tx = tid & 15, ty = tid >> 4;
  const int lr = tid >> 2, lc = (tid & 3) * 4;
  float acc[4][4] = {};
  for (int k0 = 0; k0 < 512; k0 += BK) {
    float4 va = *(const float4*)(Abase + (size_t)(arow0 + lr) * 1536 + k0 + lc);
    float4 vb = *(const float4*)(Wq + (size_t)(col0 + lr) * 512 + k0 + lc);
    Ast[lc + 0][lr] = va.x; Ast[lc + 1][lr] = va.y;
    Ast[lc + 2][lr] = va.z; Ast[lc + 3][lr] = va.w;
    Bst[lc + 0][lr] = vb.x; Bst[lc + 1][lr] = vb.y;
    Bst[lc + 2][lr] = vb.z; Bst[lc + 3][lr] = vb.w;
    __syncthreads();
#pragma unroll
    for (int k = 0; k < BK; ++k) {
      float4 a4 = *(const float4*)&Ast[k][ty * 4];
      float4 b4 = *(const float4*)&Bst[k][tx * 4];
      float a[4] = {a4.x, a4.y, a4.z, a4.w};
      float bb[4] = {b4.x, b4.y, b4.z, b4.w};
#pragma unroll
      for (int i = 0; i < 4; ++i)
#pragma unroll
        for (int j = 0; j < 4; ++j) acc[i][j] += a[i] * bb[j];
    }
    __syncthreads();
  }
#pragma unroll
  for (int i = 0; i < 4; ++i) {
    float4 o;
    o.x = acc[i][0]; o.y = acc[i][1]; o.z = acc[i][2]; o.w = acc[i][3];
    *(float4*)(M2T + (size_t)(row0 + ty * 4 + i) * 512 + col0 + tx * 4) = o;
  }
}

// ---------------- V[b,c] = dot(Hc[b,:], M2T[c,:])  (4096x1024, K=512) ------
// 64x64 tile, BK=32, 4x4 micro -> 1024 blocks (4/CU), 2-way-max LDS reads.
// Per-thread k-ascending FMA chain == previous version -> V bit-identical.
__global__ __launch_bounds__(256) void gemm_v(const float* __restrict__ A,
                                              const float* __restrict__ Bm,
                                              float* __restrict__ C) {
  constexpr int BK = 32, LDT = 68;  // 64 + 4 pad (17 float4 -> rows 16B-aligned)
  __shared__ float Ast[BK][LDT];
  __shared__ float Bst[BK][LDT];
  const int tid = threadIdx.x;
  const int row0 = blockIdx.y * 64;      // b rows
  const int col0 = blockIdx.x * 64;      // c cols
  const int tx = tid & 15, ty = tid >> 4;
  const int lr = tid >> 3;               // 0..31
  const int lc = (tid & 7) * 4;          // 0,4,..,28
  float acc[4][4] = {};
  for (int k0 = 0; k0 < 512; k0 += BK) {
    const float4 va0 = *(const float4*)(A + (size_t)(row0 + lr) * 512 + k0 + lc);
    const float4 va1 = *(const float4*)(A + (size_t)(row0 + lr + 32) * 512 + k0 + lc);
    const float4 vb0 = *(const float4*)(Bm + (size_t)(col0 + lr) * 512 + k0 + lc);
    const float4 vb1 = *(const float4*)(Bm + (size_t)(col0 + lr + 32) * 512 + k0 + lc);
    Ast[lc + 0][lr] = va0.x; Ast[lc + 1][lr] = va0.y;
    Ast[lc + 2][lr] = va0.z; Ast[lc + 3][lr] = va0.w;
    Ast[lc + 0][lr + 32] = va1.x; Ast[lc + 1][lr + 32] = va1.y;
    Ast[lc + 2][lr + 32] = va1.z; Ast[lc + 3][lr + 32] = va1.w;
    Bst[lc + 0][lr] = vb0.x; Bst[lc + 1][lr] = vb0.y;
    Bst[lc + 2][lr] = vb0.z; Bst[lc + 3][lr] = vb0.w;
    Bst[lc + 0][lr + 32] = vb1.x; Bst[lc + 1][lr + 32] = vb1.y;
    Bst[lc + 2][lr + 32] = vb1.z; Bst[lc + 3][lr + 32] = vb1.w;
    __syncthreads();
#pragma unroll
    for (int k = 0; k < BK; ++k) {
      const float4 a4 = *(const float4*)&Ast[k][ty * 4];
      const float4 b4 = *(const float4*)&Bst[k][tx * 4];
      const float a[4] = {a4.x, a4.y, a4.z, a4.w};
      const float bb[4] = {b4.x, b4.y, b4.z, b4.w};
#pragma unroll
      for (int i = 0; i < 4; ++i)
#pragma unroll
        for (int j = 0; j < 4; ++j) acc[i][j] += a[i] * bb[j];
    }
    __syncthreads();
  }
#pragma unroll
  for (int i = 0; i < 4; ++i) {
    float4 o;
    o.x = acc[i][0]; o.y = acc[i][1]; o.z = acc[i][2]; o.w = acc[i][3];
    *(float4*)(C + (size_t)(row0 + ty * 4 + i) * 1024 + col0 + tx * 4) = o;
  }
}

// ---------------- inverted index: node -> list of (b*32+m) -----------------
__global__ __launch_bounds__(256) void build_index(
    const int* __restrict__ neigh, const int* __restrict__ lens,
    int* __restrict__ cnt, int* __restrict__ bucket,
    int* __restrict__ ovf_cnt, int* __restrict__ ovf_list) {
  const int t = blockIdx.x * 256 + threadIdx.x;   // t in [0, B*M)
  const int b = t >> 5, m = t & 31;
  if (m < lens[b]) {
    const int n = neigh[t];
    const int slot = atomicAdd(&cnt[n], 1);
    if (slot < CAP) bucket[n * CAP + slot] = t;
    else { const int o = atomicAdd(ovf_cnt, 1); ovf_list[o] = t; }
  }
}

// ---------------- streaming compat: one wave per node ----------------------
__global__ __launch_bounds__(256) void stream_compat(
    const float* __restrict__ hs, const float* __restrict__ hd,
    const float* __restrict__ V, const int* __restrict__ cnt,
    const int* __restrict__ bucket, float* __restrict__ compat) {
  const int n = blockIdx.x * 4 + (threadIdx.x >> 6);   // node per wave
  const int lane = threadIdx.x & 63;
  const int c = cnt[n];
  if (c == 0) return;
  const float4* a4 = (const float4*)(hs + (size_t)n * HDIM);
  const float4* c4 = (const float4*)(hd + (size_t)n * HDIM);
  const float4 a0 = a4[lane * 2], a1 = a4[lane * 2 + 1];
  const float4 b0 = c4[lane * 2], b1 = c4[lane * 2 + 1];
  const int cc = (c < CAP) ? c : CAP;
  for (int e = 0; e < cc; ++e) {
    const int t = bucket[n * CAP + e];
    const int b = t >> 5;
    const float4* vrow = (const float4*)(V + (size_t)b * (2 * HDIM));
    const float4 w0 = vrow[lane * 2], w1 = vrow[lane * 2 + 1];
    const float4 u0 = vrow[128 + lane * 2], u1 = vrow[128 + lane * 2 + 1];
    float acc = a0.x * w0.x + a0.y * w0.y + a0.z * w0.z + a0.w * w0.w
              + a1.x * w1.x + a1.y * w1.y + a1.z * w1.z + a1.w * w1.w
              + b0.x * u0.x + b0.y * u0.y + b0.z * u0.z + b0.w * u0.w
              + b1.x * u1.x + b1.y * u1.y + b1.z * u1.z + b1.w * u1.w;
#pragma unroll
    for (int off = 32; off >= 1; off >>= 1) acc += __shfl_xor(acc, off);
    if (lane == 0) compat[t] = acc;
  }
}

// ---------------- overflow path (virtually never executes) -----------------
__global__ __launch_bounds__(256) void ovf_compat(
    const float* __restrict__ hs, const float* __restrict__ hd,
    const float* __restrict__ V, const int* __restrict__ ovf_cnt,
    const int* __restrict__ ovf_list, const int* __restrict__ neigh,
    float* __restrict__ compat) {
  const int nw = *ovf_cnt;
  const int lane = threadIdx.x & 63;
  for (int e = blockIdx.x * 4 + (threadIdx.x >> 6); e < nw; e += gridDim.x * 4) {
    const int t = ovf_list[e];
    const int b = t >> 5;
    const int n = neigh[t];
    const float4* a4 = (const float4*)(hs + (size_t)n * HDIM);
    const float4* c4 = (const float4*)(hd + (size_t)n * HDIM);
    const float4 a0 = a4[lane * 2], a1 = a4[lane * 2 + 1];
    const float4 b0 = c4[lane * 2], b1 = c4[lane * 2 + 1];
    const float4* vrow = (const float4*)(V + (size_t)b * (2 * HDIM));
    const float4 w0 = vrow[lane * 2], w1 = vrow[lane * 2 + 1];
    const float4 u0 = vrow[128 + lane * 2], u1 = vrow[128 + lane * 2 + 1];
    float acc = a0.x * w0.x + a0.y * w0.y + a0.z * w0.z + a0.w * w0.w
              + a1.x * w1.x + a1.y * w1.y + a1.z * w1.z + a1.w * w1.w
              + b0.x * u0.x + b0.y * u0.y + b0.z * u0.z + b0.w * u0.w
              + b1.x * u1.x + b1.y * u1.y + b1.z * u1.z + b1.w * u1.w;
#pragma unroll
    for (int off = 32; off >= 1; off >>= 1) acc += __shfl_xor(acc, off);
    if (lane == 0) compat[t] = acc;
  }
}

// ---------------- per-b: Gumbel argmax + log-softmax (one wave per b) ------
__global__ __launch_bounds__(256) void finalize_kernel(
    const float* __restrict__ compat, const int* __restrict__ neigh,
    const int* __restrict__ lengths, const int* __restrict__ cur,
    float* __restrict__ out) {
  const int b = blockIdx.x * 4 + (threadIdx.x >> 6);
  const int tid = threadIdx.x & 63;
  const int len = lengths[b];
  const bool valid = tid < NM;
  const float NEGMAX = -3.402823466e38f;
  float logit = NEGMAX;
  if (valid) {
    const float cm = compat[b * NM + tid] / 22.62741699796952f;  // / sqrt(512)
    logit = (tid < len) ? cm : -1e9f;
  }
  float z = NEGMAX;
  int zi = 1 << 20;
  if (valid) {
    // JAX partitionable threefry: counter = 64-bit flat index,
    // draw = out0 ^ out1 of threefry2x32(key=(0,1), (hi, lo)).
    const unsigned i_lo = (unsigned)b * 32u + (unsigned)tid;
    unsigned x0 = 0u;
    unsigned x1 = i_lo;
    threefry2x32(x0, x1);
    const unsigned bits = x0 ^ x1;
    const float fu = __uint_as_float((bits >> 9) | 0x3f800000u) - 1.0f;
    const float uu = fmaxf(1e-8f, fu + 1e-8f);
    const float g = -logf(-logf(uu));
    z = logit + g;
    zi = tid;
  }
#pragma unroll
  for (int off = 32; off >= 1; off >>= 1) {
    const float oz = __shfl_xor(z, off);
    const int oi = __shfl_xor(zi, off);
    if (oz > z || (oz == z && oi < zi)) { z = oz; zi = oi; }
  }
  float ml = logit;
#pragma unroll
  for (int off = 32; off >= 1; off >>= 1) ml = fmaxf(ml, __shfl_xor(ml, off));
  float ex = valid ? expf(logit - ml) : 0.f;
#pragma unroll
  for (int off = 32; off >= 1; off >>= 1) ex += __shfl_xor(ex, off);
  const float lsel = __shfl(logit, zi);
  if (tid == 0) {
    float lp = lsel - ml - logf(ex);
    int act = neigh[b * NM + zi];
    if (len <= 0) { act = cur[b]; lp = 0.f; }
    out[b] = (float)act;
    out[NBATCH + b] = lp;
  }
}

extern "C" void kernel_launch(void* const* d_in, const int* in_sizes, int n_in,
                              void* d_out, int out_size, void* d_ws, size_t ws_size,
                              hipStream_t stream) {
  const float* hs = (const float*)d_in[0];
  const float* hd = (const float*)d_in[1];
  const float* Ws = (const float*)d_in[2];
  const float* Wd = (const float*)d_in[3];
  const float* Wq = (const float*)d_in[4];
  const int* cur = (const int*)d_in[6];
  const int* neigh = (const int*)d_in[7];
  const int* lens = (const int*)d_in[8];
  float* out = (float*)d_out;

  char* ws = (char*)d_ws;
  size_t off = 0;
  int* cnt = (int*)(ws + off);        off += (size_t)NNODE * 4;        // 256 KB
  int* ovf_cnt = (int*)(ws + off);    off += 256;                      // pad
  int* bucket = (int*)(ws + off);     off += (size_t)NNODE * CAP * 4;  // 4 MB
  int* ovf_list = (int*)(ws + off);   off += (size_t)NBATCH * NM * 4;  // 512 KB
  float* compat = (float*)(ws + off); off += (size_t)NBATCH * NM * 4;  // 512 KB
  float* Hc = (float*)(ws + off);     off += (size_t)NBATCH * HDIM * 4;    // 8 MB
  float* M2T = (float*)(ws + off);    off += (size_t)1024 * 512 * 4;       // 2 MB
  float* V = (float*)(ws + off);      off += (size_t)NBATCH * 2 * HDIM * 4; // 16 MB

  hipLaunchKernelGGL(zero_cnt, dim3(64), dim3(256), 0, stream, cnt, ovf_cnt);
  hipLaunchKernelGGL(build_index, dim3(NBATCH * NM / 256), dim3(256), 0, stream,
                     neigh, lens, cnt, bucket, ovf_cnt, ovf_list);
  hipLaunchKernelGGL(gemm_b1, dim3(8, 16), dim3(256), 0, stream, Ws, Wd, Wq, M2T);
  hipLaunchKernelGGL(gather_hc, dim3(NBATCH), dim3(128), 0, stream, hs, hd, cur, Hc);
  hipLaunchKernelGGL(gemm_v, dim3(16, 64), dim3(256), 0, stream, Hc, M2T, V);
  hipLaunchKernelGGL(stream_compat, dim3(NNODE / 4), dim3(256), 0, stream,
                     hs, hd, V, cnt, bucket, compat);
  hipLaunchKernelGGL(ovf_compat, dim3(32), dim3(256), 0, stream,
                     hs, hd, V, ovf_cnt, ovf_list, neigh, compat);
  hipLaunchKernelGGL(finalize_kernel, dim3(NBATCH / 4), dim3(256), 0, stream,
                     compat, neigh, lens, cur, out);
}

// Round 7
// 168.069 us; speedup vs baseline: 1.1044x; 1.0380x over previous
//
#include <hip/hip_runtime.h>
#include <cstdint>
#include <cstddef>

#define HDIM 512
#define NM 32
#define NBATCH 4096
#define NNODE 65536
#define CAP 16

typedef float v4f __attribute__((ext_vector_type(4)));

// ---------------- Threefry-2x32-20, key = (0,1)  (jax.random.key(1)) -------
__device__ __forceinline__ unsigned rotl32(unsigned x, unsigned d) {
  return (x << d) | (x >> (32u - d));
}

__device__ __forceinline__ void threefry2x32(unsigned& x0, unsigned& x1) {
  const unsigned ks0 = 0u, ks1 = 1u, ks2 = 0x1BD11BDBu; // 0^1^0x1BD11BDA
  x0 += ks0; x1 += ks1;
#define TF_RND(r) { x0 += x1; x1 = rotl32(x1, (r)); x1 ^= x0; }
  TF_RND(13) TF_RND(15) TF_RND(26) TF_RND(6)
  x0 += ks1; x1 += ks2 + 1u;
  TF_RND(17) TF_RND(29) TF_RND(16) TF_RND(24)
  x0 += ks2; x1 += ks0 + 2u;
  TF_RND(13) TF_RND(15) TF_RND(26) TF_RND(6)
  x0 += ks0; x1 += ks1 + 3u;
  TF_RND(17) TF_RND(29) TF_RND(16) TF_RND(24)
  x0 += ks1; x1 += ks2 + 4u;
  TF_RND(13) TF_RND(15) TF_RND(26) TF_RND(6)
  x0 += ks2; x1 += ks0 + 5u;
#undef TF_RND
}

// ---------------- zero cnt + ovf_cnt ---------------------------------------
__global__ __launch_bounds__(256) void zero_cnt(int* __restrict__ cnt,
                                                int* __restrict__ ovf_cnt) {
  const int t = blockIdx.x * 256 + threadIdx.x;   // 64 blocks -> 16384 int4
  ((int4*)cnt)[t] = make_int4(0, 0, 0, 0);
  if (t == 0) *ovf_cnt = 0;
}

// ---------------- M2T[c,e] = dot(W*_kvl[c, 0:512], Wq[e, 0:512]) -----------
__global__ __launch_bounds__(256) void gemm_b1(const float* __restrict__ Ws,
                                               const float* __restrict__ Wd,
                                               const float* __restrict__ Wq,
                                               float* __restrict__ M2T) {
  constexpr int BK = 16, LDT = 68;  // 64 + 4 pad
  __shared__ float Ast[BK][LDT];
  __shared__ float Bst[BK][LDT];
  const int tid = threadIdx.x;
  const int row0 = blockIdx.y * 64;      // combined c row
  const int col0 = blockIdx.x * 64;      // e
  const float* Abase = (row0 < 512) ? Ws : Wd;
  const int arow0 = (row0 < 512) ? row0 : row0 - 512;
  const int tx = tid & 15, ty = tid >> 4;
  const int lr = tid >> 2, lc = (tid & 3) * 4;
  float acc[4][4] = {};
  for (int k0 = 0; k0 < 512; k0 += BK) {
    float4 va = *(const float4*)(Abase + (size_t)(arow0 + lr) * 1536 + k0 + lc);
    float4 vb = *(const float4*)(Wq + (size_t)(col0 + lr) * 512 + k0 + lc);
    Ast[lc + 0][lr] = va.x; Ast[lc + 1][lr] = va.y;
    Ast[lc + 2][lr] = va.z; Ast[lc + 3][lr] = va.w;
    Bst[lc + 0][lr] = vb.x; Bst[lc + 1][lr] = vb.y;
    Bst[lc + 2][lr] = vb.z; Bst[lc + 3][lr] = vb.w;
    __syncthreads();
#pragma unroll
    for (int k = 0; k < BK; ++k) {
      float4 a4 = *(const float4*)&Ast[k][ty * 4];
      float4 b4 = *(const float4*)&Bst[k][tx * 4];
      float a[4] = {a4.x, a4.y, a4.z, a4.w};
      float bb[4] = {b4.x, b4.y, b4.z, b4.w};
#pragma unroll
      for (int i = 0; i < 4; ++i)
#pragma unroll
        for (int j = 0; j < 4; ++j) acc[i][j] += a[i] * bb[j];
    }
    __syncthreads();
  }
#pragma unroll
  for (int i = 0; i < 4; ++i) {
    float4 o;
    o.x = acc[i][0]; o.y = acc[i][1]; o.z = acc[i][2]; o.w = acc[i][3];
    *(float4*)(M2T + (size_t)(row0 + ty * 4 + i) * 512 + col0 + tx * 4) = o;
  }
}

// ---------------- V[b,c] = dot(hs[cur[b]]+hd[cur[b]], M2T[c,:]) ------------
// Fused Hc gather: A row r = hs[cur[r]] + hd[cur[r]] computed on the fly
// (same add order as the old gather_hc -> V bit-identical).
// 64x64 tile, BK=32, 4x4 micro -> 1024 blocks (4/CU).
__global__ __launch_bounds__(256) void gemm_v(const float* __restrict__ hs,
                                              const float* __restrict__ hd,
                                              const int* __restrict__ cur,
                                              const float* __restrict__ Bm,
                                              float* __restrict__ C) {
  constexpr int BK = 32, LDT = 68;  // 64 + 4 pad
  __shared__ float Ast[BK][LDT];
  __shared__ float Bst[BK][LDT];
  const int tid = threadIdx.x;
  const int row0 = blockIdx.y * 64;      // b rows
  const int col0 = blockIdx.x * 64;      // c cols
  const int tx = tid & 15, ty = tid >> 4;
  const int lr = tid >> 3;               // 0..31
  const int lc = (tid & 7) * 4;          // 0,4,..,28
  const size_t n0 = (size_t)cur[row0 + lr] * HDIM;
  const size_t n1 = (size_t)cur[row0 + lr + 32] * HDIM;
  float acc[4][4] = {};
  for (int k0 = 0; k0 < 512; k0 += BK) {
    const float4 s0 = *(const float4*)(hs + n0 + k0 + lc);
    const float4 d0 = *(const float4*)(hd + n0 + k0 + lc);
    const float4 s1 = *(const float4*)(hs + n1 + k0 + lc);
    const float4 d1 = *(const float4*)(hd + n1 + k0 + lc);
    const float4 vb0 = *(const float4*)(Bm + (size_t)(col0 + lr) * 512 + k0 + lc);
    const float4 vb1 = *(const float4*)(Bm + (size_t)(col0 + lr + 32) * 512 + k0 + lc);
    Ast[lc + 0][lr] = s0.x + d0.x; Ast[lc + 1][lr] = s0.y + d0.y;
    Ast[lc + 2][lr] = s0.z + d0.z; Ast[lc + 3][lr] = s0.w + d0.w;
    Ast[lc + 0][lr + 32] = s1.x + d1.x; Ast[lc + 1][lr + 32] = s1.y + d1.y;
    Ast[lc + 2][lr + 32] = s1.z + d1.z; Ast[lc + 3][lr + 32] = s1.w + d1.w;
    Bst[lc + 0][lr] = vb0.x; Bst[lc + 1][lr] = vb0.y;
    Bst[lc + 2][lr] = vb0.z; Bst[lc + 3][lr] = vb0.w;
    Bst[lc + 0][lr + 32] = vb1.x; Bst[lc + 1][lr + 32] = vb1.y;
    Bst[lc + 2][lr + 32] = vb1.z; Bst[lc + 3][lr + 32] = vb1.w;
    __syncthreads();
#pragma unroll
    for (int k = 0; k < BK; ++k) {
      const float4 a4 = *(const float4*)&Ast[k][ty * 4];
      const float4 b4 = *(const float4*)&Bst[k][tx * 4];
      const float a[4] = {a4.x, a4.y, a4.z, a4.w};
      const float bb[4] = {b4.x, b4.y, b4.z, b4.w};
#pragma unroll
      for (int i = 0; i < 4; ++i)
#pragma unroll
        for (int j = 0; j < 4; ++j) acc[i][j] += a[i] * bb[j];
    }
    __syncthreads();
  }
#pragma unroll
  for (int i = 0; i < 4; ++i) {
    float4 o;
    o.x = acc[i][0]; o.y = acc[i][1]; o.z = acc[i][2]; o.w = acc[i][3];
    *(float4*)(C + (size_t)(row0 + ty * 4 + i) * 1024 + col0 + tx * 4) = o;
  }
}

// ---------------- inverted index: node -> list of (b*32+m) -----------------
__global__ __launch_bounds__(256) void build_index(
    const int* __restrict__ neigh, const int* __restrict__ lens,
    int* __restrict__ cnt, int* __restrict__ bucket,
    int* __restrict__ ovf_cnt, int* __restrict__ ovf_list) {
  const int t = blockIdx.x * 256 + threadIdx.x;   // t in [0, B*M)
  const int b = t >> 5, m = t & 31;
  if (m < lens[b]) {
    const int n = neigh[t];
    const int slot = atomicAdd(&cnt[n], 1);
    if (slot < CAP) bucket[n * CAP + slot] = t;
    else { const int o = atomicAdd(ovf_cnt, 1); ovf_list[o] = t; }
  }
}

// ---------------- streaming compat: one wave per node + ovf drain ----------
// hs/hd rows are read exactly once -> nontemporal; V stays cache-hot.
__global__ __launch_bounds__(256) void stream_compat(
    const float* __restrict__ hs, const float* __restrict__ hd,
    const float* __restrict__ V, const int* __restrict__ cnt,
    const int* __restrict__ bucket, const int* __restrict__ ovf_cnt,
    const int* __restrict__ ovf_list, const int* __restrict__ neigh,
    float* __restrict__ compat) {
  const int n = blockIdx.x * 4 + (threadIdx.x >> 6);   // node per wave
  const int lane = threadIdx.x & 63;
  const int c = cnt[n];
  if (c != 0) {
    const v4f* a4 = (const v4f*)(hs + (size_t)n * HDIM);
    const v4f* c4 = (const v4f*)(hd + (size_t)n * HDIM);
    const v4f a0 = __builtin_nontemporal_load(a4 + lane * 2);
    const v4f a1 = __builtin_nontemporal_load(a4 + lane * 2 + 1);
    const v4f b0 = __builtin_nontemporal_load(c4 + lane * 2);
    const v4f b1 = __builtin_nontemporal_load(c4 + lane * 2 + 1);
    const int cc = (c < CAP) ? c : CAP;
    for (int e = 0; e < cc; ++e) {
      const int t = bucket[n * CAP + e];
      const int b = t >> 5;
      const float4* vrow = (const float4*)(V + (size_t)b * (2 * HDIM));
      const float4 w0 = vrow[lane * 2], w1 = vrow[lane * 2 + 1];
      const float4 u0 = vrow[128 + lane * 2], u1 = vrow[128 + lane * 2 + 1];
      float acc = a0.x * w0.x + a0.y * w0.y + a0.z * w0.z + a0.w * w0.w
                + a1.x * w1.x + a1.y * w1.y + a1.z * w1.z + a1.w * w1.w
                + b0.x * u0.x + b0.y * u0.y + b0.z * u0.z + b0.w * u0.w
                + b1.x * u1.x + b1.y * u1.y + b1.z * u1.z + b1.w * u1.w;
#pragma unroll
      for (int off = 32; off >= 1; off >>= 1) acc += __shfl_xor(acc, off);
      if (lane == 0) compat[t] = acc;
    }
  }
  // overflow drain (ovf is ~always empty; disjoint t-set -> no race)
  if (blockIdx.x < 32) {
    const int nw = *ovf_cnt;
    for (int e = blockIdx.x * 4 + (threadIdx.x >> 6); e < nw; e += 128) {
      const int t = ovf_list[e];
      const int b = t >> 5;
      const int nn = neigh[t];
      const float4* a4 = (const float4*)(hs + (size_t)nn * HDIM);
      const float4* c4 = (const float4*)(hd + (size_t)nn * HDIM);
      const float4 a0 = a4[lane * 2], a1 = a4[lane * 2 + 1];
      const float4 b0 = c4[lane * 2], b1 = c4[lane * 2 + 1];
      const float4* vrow = (const float4*)(V + (size_t)b * (2 * HDIM));
      const float4 w0 = vrow[lane * 2], w1 = vrow[lane * 2 + 1];
      const float4 u0 = vrow[128 + lane * 2], u1 = vrow[128 + lane * 2 + 1];
      float acc = a0.x * w0.x + a0.y * w0.y + a0.z * w0.z + a0.w * w0.w
                + a1.x * w1.x + a1.y * w1.y + a1.z * w1.z + a1.w * w1.w
                + b0.x * u0.x + b0.y * u0.y + b0.z * u0.z + b0.w * u0.w
                + b1.x * u1.x + b1.y * u1.y + b1.z * u1.z + b1.w * u1.w;
#pragma unroll
      for (int off = 32; off >= 1; off >>= 1) acc += __shfl_xor(acc, off);
      if (lane == 0) compat[t] = acc;
    }
  }
}

// ---------------- per-b: Gumbel argmax + log-softmax (one wave per b) ------
__global__ __launch_bounds__(256) void finalize_kernel(
    const float* __restrict__ compat, const int* __restrict__ neigh,
    const int* __restrict__ lengths, const int* __restrict__ cur,
    float* __restrict__ out) {
  const int b = blockIdx.x * 4 + (threadIdx.x >> 6);
  const int tid = threadIdx.x & 63;
  const int len = lengths[b];
  const bool valid = tid < NM;
  const float NEGMAX = -3.402823466e38f;
  float logit = NEGMAX;
  if (valid) {
    const float cm = compat[b * NM + tid] / 22.62741699796952f;  // / sqrt(512)
    logit = (tid < len) ? cm : -1e9f;
  }
  float z = NEGMAX;
  int zi = 1 << 20;
  if (valid) {
    // JAX partitionable threefry: counter = 64-bit flat index,
    // draw = out0 ^ out1 of threefry2x32(key=(0,1), (hi, lo)).
    const unsigned i_lo = (unsigned)b * 32u + (unsigned)tid;
    unsigned x0 = 0u;
    unsigned x1 = i_lo;
    threefry2x32(x0, x1);
    const unsigned bits = x0 ^ x1;
    const float fu = __uint_as_float((bits >> 9) | 0x3f800000u) - 1.0f;
    const float uu = fmaxf(1e-8f, fu + 1e-8f);
    const float g = -logf(-logf(uu));
    z = logit + g;
    zi = tid;
  }
#pragma unroll
  for (int off = 32; off >= 1; off >>= 1) {
    const float oz = __shfl_xor(z, off);
    const int oi = __shfl_xor(zi, off);
    if (oz > z || (oz == z && oi < zi)) { z = oz; zi = oi; }
  }
  float ml = logit;
#pragma unroll
  for (int off = 32; off >= 1; off >>= 1) ml = fmaxf(ml, __shfl_xor(ml, off));
  float ex = valid ? expf(logit - ml) : 0.f;
#pragma unroll
  for (int off = 32; off >= 1; off >>= 1) ex += __shfl_xor(ex, off);
  const float lsel = __shfl(logit, zi);
  if (tid == 0) {
    float lp = lsel - ml - logf(ex);
    int act = neigh[b * NM + zi];
    if (len <= 0) { act = cur[b]; lp = 0.f; }
    out[b] = (float)act;
    out[NBATCH + b] = lp;
  }
}

extern "C" void kernel_launch(void* const* d_in, const int* in_sizes, int n_in,
                              void* d_out, int out_size, void* d_ws, size_t ws_size,
                              hipStream_t stream) {
  const float* hs = (const float*)d_in[0];
  const float* hd = (const float*)d_in[1];
  const float* Ws = (const float*)d_in[2];
  const float* Wd = (const float*)d_in[3];
  const float* Wq = (const float*)d_in[4];
  const int* cur = (const int*)d_in[6];
  const int* neigh = (const int*)d_in[7];
  const int* lens = (const int*)d_in[8];
  float* out = (float*)d_out;

  char* ws = (char*)d_ws;
  size_t off = 0;
  int* cnt = (int*)(ws + off);        off += (size_t)NNODE * 4;        // 256 KB
  int* ovf_cnt = (int*)(ws + off);    off += 256;                      // pad
  int* bucket = (int*)(ws + off);     off += (size_t)NNODE * CAP * 4;  // 4 MB
  int* ovf_list = (int*)(ws + off);   off += (size_t)NBATCH * NM * 4;  // 512 KB
  float* compat = (float*)(ws + off); off += (size_t)NBATCH * NM * 4;  // 512 KB
  float* M2T = (float*)(ws + off);    off += (size_t)1024 * 512 * 4;       // 2 MB
  float* V = (float*)(ws + off);      off += (size_t)NBATCH * 2 * HDIM * 4; // 16 MB

  hipLaunchKernelGGL(zero_cnt, dim3(64), dim3(256), 0, stream, cnt, ovf_cnt);
  hipLaunchKernelGGL(build_index, dim3(NBATCH * NM / 256), dim3(256), 0, stream,
                     neigh, lens, cnt, bucket, ovf_cnt, ovf_list);
  hipLaunchKernelGGL(gemm_b1, dim3(8, 16), dim3(256), 0, stream, Ws, Wd, Wq, M2T);
  hipLaunchKernelGGL(gemm_v, dim3(16, 64), dim3(256), 0, stream, hs, hd, cur, M2T, V);
  hipLaunchKernelGGL(stream_compat, dim3(NNODE / 4), dim3(256), 0, stream,
                     hs, hd, V, cnt, bucket, ovf_cnt, ovf_list, neigh, compat);
  hipLaunchKernelGGL(finalize_kernel, dim3(NBATCH / 4), dim3(256), 0, stream,
                     compat, neigh, lens, cur, out);
}

// Round 9
// 166.925 us; speedup vs baseline: 1.1120x; 1.0069x over previous
//
#include <hip/hip_runtime.h>
#include <cstdint>
#include <cstddef>

#define HDIM 512
#define NM 32
#define NBATCH 4096
#define NNODE 65536
#define CAP 16

typedef float v4f __attribute__((ext_vector_type(4)));

// ---------------- Threefry-2x32-20, key = (0,1)  (jax.random.key(1)) -------
__device__ __forceinline__ unsigned rotl32(unsigned x, unsigned d) {
  return (x << d) | (x >> (32u - d));
}

__device__ __forceinline__ void threefry2x32(unsigned& x0, unsigned& x1) {
  const unsigned ks0 = 0u, ks1 = 1u, ks2 = 0x1BD11BDBu; // 0^1^0x1BD11BDA
  x0 += ks0; x1 += ks1;
#define TF_RND(r) { x0 += x1; x1 = rotl32(x1, (r)); x1 ^= x0; }
  TF_RND(13) TF_RND(15) TF_RND(26) TF_RND(6)
  x0 += ks1; x1 += ks2 + 1u;
  TF_RND(17) TF_RND(29) TF_RND(16) TF_RND(24)
  x0 += ks2; x1 += ks0 + 2u;
  TF_RND(13) TF_RND(15) TF_RND(26) TF_RND(6)
  x0 += ks0; x1 += ks1 + 3u;
  TF_RND(17) TF_RND(29) TF_RND(16) TF_RND(24)
  x0 += ks1; x1 += ks2 + 4u;
  TF_RND(13) TF_RND(15) TF_RND(26) TF_RND(6)
  x0 += ks2; x1 += ks0 + 5u;
#undef TF_RND
}

// ---------------- zero cnt + ovf_cnt ---------------------------------------
__global__ __launch_bounds__(256) void zero_cnt(int* __restrict__ cnt,
                                                int* __restrict__ ovf_cnt) {
  const int t = blockIdx.x * 256 + threadIdx.x;   // 64 blocks -> 16384 int4
  ((int4*)cnt)[t] = make_int4(0, 0, 0, 0);
  if (t == 0) *ovf_cnt = 0;
}

// ---------------- fused: gemm_b1 (blocks 0..127) + build_index (128..639) --
// gemm_b1: M2T[c,e] = dot(W*_kvl[c, 0:512], Wq[e, 0:512])
// build:   inverted index node -> list of (b*32+m)
__global__ __launch_bounds__(256) void b1_and_index(
    const float* __restrict__ Ws, const float* __restrict__ Wd,
    const float* __restrict__ Wq, float* __restrict__ M2T,
    const int* __restrict__ neigh, const int* __restrict__ lens,
    int* __restrict__ cnt, int* __restrict__ bucket,
    int* __restrict__ ovf_cnt, int* __restrict__ ovf_list) {
  constexpr int BK = 16, LDT = 68;  // 64 + 4 pad
  __shared__ float Ast[BK][LDT];
  __shared__ float Bst[BK][LDT];
  const int bid = blockIdx.x;
  const int tid = threadIdx.x;
  if (bid >= 128) {
    // ---- build_index part ----
    const int t = (bid - 128) * 256 + tid;   // t in [0, B*M)
    const int b = t >> 5, m = t & 31;
    if (m < lens[b]) {
      const int n = neigh[t];
      const int slot = atomicAdd(&cnt[n], 1);
      if (slot < CAP) bucket[n * CAP + slot] = t;
      else { const int o = atomicAdd(ovf_cnt, 1); ovf_list[o] = t; }
    }
    return;
  }
  // ---- gemm_b1 part ----
  const int row0 = (bid >> 3) * 64;      // combined c row (16 row-tiles)
  const int col0 = (bid & 7) * 64;       // e (8 col-tiles)
  const float* Abase = (row0 < 512) ? Ws : Wd;
  const int arow0 = (row0 < 512) ? row0 : row0 - 512;
  const int tx = tid & 15, ty = tid >> 4;
  const int lr = tid >> 2, lc = (tid & 3) * 4;
  float acc[4][4] = {};
  for (int k0 = 0; k0 < 512; k0 += BK) {
    float4 va = *(const float4*)(Abase + (size_t)(arow0 + lr) * 1536 + k0 + lc);
    float4 vb = *(const float4*)(Wq + (size_t)(col0 + lr) * 512 + k0 + lc);
    Ast[lc + 0][lr] = va.x; Ast[lc + 1][lr] = va.y;
    Ast[lc + 2][lr] = va.z; Ast[lc + 3][lr] = va.w;
    Bst[lc + 0][lr] = vb.x; Bst[lc + 1][lr] = vb.y;
    Bst[lc + 2][lr] = vb.z; Bst[lc + 3][lr] = vb.w;
    __syncthreads();
#pragma unroll
    for (int k = 0; k < BK; ++k) {
      float4 a4 = *(const float4*)&Ast[k][ty * 4];
      float4 b4 = *(const float4*)&Bst[k][tx * 4];
      float a[4] = {a4.x, a4.y, a4.z, a4.w};
      float bb[4] = {b4.x, b4.y, b4.z, b4.w};
#pragma unroll
      for (int i = 0; i < 4; ++i)
#pragma unroll
        for (int j = 0; j < 4; ++j) acc[i][j] += a[i] * bb[j];
    }
    __syncthreads();
  }
#pragma unroll
  for (int i = 0; i < 4; ++i) {
    float4 o;
    o.x = acc[i][0]; o.y = acc[i][1]; o.z = acc[i][2]; o.w = acc[i][3];
    *(float4*)(M2T + (size_t)(row0 + ty * 4 + i) * 512 + col0 + tx * 4) = o;
  }
}

// ---------------- V[b,c] = dot(hs[cur[b]]+hd[cur[b]], M2T[c,:]) ------------
// Double-buffered: global loads for tile t+1 issue right after the single
// per-iter barrier and complete under tile t's 32x16 FMA compute.
// Per-thread k-ascending FMA chain unchanged -> V bit-identical.
// Grid: 1024 blocks flattened; XCD-swizzled so each XCD keeps a row-panel.
__global__ __launch_bounds__(256) void gemm_v(const float* __restrict__ hs,
                                              const float* __restrict__ hd,
                                              const int* __restrict__ cur,
                                              const float* __restrict__ Bm,
                                              float* __restrict__ C) {
  constexpr int BK = 32, LDT = 68;  // 64 + 4 pad
  __shared__ float Ast[2][BK][LDT];
  __shared__ float Bst[2][BK][LDT];
  const int tid = threadIdx.x;
  const int swz = (blockIdx.x & 7) * 128 + (blockIdx.x >> 3);  // 1024 % 8 == 0
  const int row0 = (swz >> 4) * 64;      // b rows (64 row-tiles)
  const int col0 = (swz & 15) * 64;      // c cols (16 col-tiles)
  const int tx = tid & 15, ty = tid >> 4;
  const int lr = tid >> 3;               // 0..31
  const int lc = (tid & 7) * 4;          // 0,4,..,28
  const size_t n0 = (size_t)cur[row0 + lr] * HDIM + lc;
  const size_t n1 = (size_t)cur[row0 + lr + 32] * HDIM + lc;
  const float* bp0 = Bm + (size_t)(col0 + lr) * 512 + lc;
  const float* bp1 = Bm + (size_t)(col0 + lr + 32) * 512 + lc;

  float4 s0 = *(const float4*)(hs + n0);
  float4 d0 = *(const float4*)(hd + n0);
  float4 s1 = *(const float4*)(hs + n1);
  float4 d1 = *(const float4*)(hd + n1);
  float4 vb0 = *(const float4*)(bp0);
  float4 vb1 = *(const float4*)(bp1);

  float acc[4][4] = {};
  int cb = 0;
#pragma unroll 1
  for (int t = 0; t < 16; ++t) {
    Ast[cb][lc + 0][lr] = s0.x + d0.x; Ast[cb][lc + 1][lr] = s0.y + d0.y;
    Ast[cb][lc + 2][lr] = s0.z + d0.z; Ast[cb][lc + 3][lr] = s0.w + d0.w;
    Ast[cb][lc + 0][lr + 32] = s1.x + d1.x; Ast[cb][lc + 1][lr + 32] = s1.y + d1.y;
    Ast[cb][lc + 2][lr + 32] = s1.z + d1.z; Ast[cb][lc + 3][lr + 32] = s1.w + d1.w;
    Bst[cb][lc + 0][lr] = vb0.x; Bst[cb][lc + 1][lr] = vb0.y;
    Bst[cb][lc + 2][lr] = vb0.z; Bst[cb][lc + 3][lr] = vb0.w;
    Bst[cb][lc + 0][lr + 32] = vb1.x; Bst[cb][lc + 1][lr + 32] = vb1.y;
    Bst[cb][lc + 2][lr + 32] = vb1.z; Bst[cb][lc + 3][lr + 32] = vb1.w;
    __syncthreads();
    if (t < 15) {
      const int k0 = (t + 1) * BK;
      s0 = *(const float4*)(hs + n0 + k0);
      d0 = *(const float4*)(hd + n0 + k0);
      s1 = *(const float4*)(hs + n1 + k0);
      d1 = *(const float4*)(hd + n1 + k0);
      vb0 = *(const float4*)(bp0 + k0);
      vb1 = *(const float4*)(bp1 + k0);
    }
#pragma unroll
    for (int k = 0; k < BK; ++k) {
      const float4 a4 = *(const float4*)&Ast[cb][k][ty * 4];
      const float4 b4 = *(const float4*)&Bst[cb][k][tx * 4];
      const float a[4] = {a4.x, a4.y, a4.z, a4.w};
      const float bb[4] = {b4.x, b4.y, b4.z, b4.w};
#pragma unroll
      for (int i = 0; i < 4; ++i)
#pragma unroll
        for (int j = 0; j < 4; ++j) acc[i][j] += a[i] * bb[j];
    }
    cb ^= 1;   // single barrier per iter is safe with 2 buffers (see theory)
  }
#pragma unroll
  for (int i = 0; i < 4; ++i) {
    float4 o;
    o.x = acc[i][0]; o.y = acc[i][1]; o.z = acc[i][2]; o.w = acc[i][3];
    *(float4*)(C + (size_t)(row0 + ty * 4 + i) * 1024 + col0 + tx * 4) = o;
  }
}

// ---------------- streaming compat: one wave per node + ovf drain ----------
// hs/hd rows are read exactly once -> nontemporal; V stays cache-hot.
__global__ __launch_bounds__(256) void stream_compat(
    const float* __restrict__ hs, const float* __restrict__ hd,
    const float* __restrict__ V, const int* __restrict__ cnt,
    const int* __restrict__ bucket, const int* __restrict__ ovf_cnt,
    const int* __restrict__ ovf_list, const int* __restrict__ neigh,
    float* __restrict__ compat) {
  const int n = blockIdx.x * 4 + (threadIdx.x >> 6);   // node per wave
  const int lane = threadIdx.x & 63;
  const int c = cnt[n];
  if (c != 0) {
    const v4f* a4 = (const v4f*)(hs + (size_t)n * HDIM);
    const v4f* c4 = (const v4f*)(hd + (size_t)n * HDIM);
    const v4f a0 = __builtin_nontemporal_load(a4 + lane * 2);
    const v4f a1 = __builtin_nontemporal_load(a4 + lane * 2 + 1);
    const v4f b0 = __builtin_nontemporal_load(c4 + lane * 2);
    const v4f b1 = __builtin_nontemporal_load(c4 + lane * 2 + 1);
    const int cc = (c < CAP) ? c : CAP;
    for (int e = 0; e < cc; ++e) {
      const int t = bucket[n * CAP + e];
      const int b = t >> 5;
      const float4* vrow = (const float4*)(V + (size_t)b * (2 * HDIM));
      const float4 w0 = vrow[lane * 2], w1 = vrow[lane * 2 + 1];
      const float4 u0 = vrow[128 + lane * 2], u1 = vrow[128 + lane * 2 + 1];
      float acc = a0.x * w0.x + a0.y * w0.y + a0.z * w0.z + a0.w * w0.w
                + a1.x * w1.x + a1.y * w1.y + a1.z * w1.z + a1.w * w1.w
                + b0.x * u0.x + b0.y * u0.y + b0.z * u0.z + b0.w * u0.w
                + b1.x * u1.x + b1.y * u1.y + b1.z * u1.z + b1.w * u1.w;
#pragma unroll
      for (int off = 32; off >= 1; off >>= 1) acc += __shfl_xor(acc, off);
      if (lane == 0) compat[t] = acc;
    }
  }
  // overflow drain (ovf is ~always empty; disjoint t-set -> no race)
  if (blockIdx.x < 32) {
    const int nw = *ovf_cnt;
    for (int e = blockIdx.x * 4 + (threadIdx.x >> 6); e < nw; e += 128) {
      const int t = ovf_list[e];
      const int b = t >> 5;
      const int nn = neigh[t];
      const float4* a4 = (const float4*)(hs + (size_t)nn * HDIM);
      const float4* c4 = (const float4*)(hd + (size_t)nn * HDIM);
      const float4 a0 = a4[lane * 2], a1 = a4[lane * 2 + 1];
      const float4 b0 = c4[lane * 2], b1 = c4[lane * 2 + 1];
      const float4* vrow = (const float4*)(V + (size_t)b * (2 * HDIM));
      const float4 w0 = vrow[lane * 2], w1 = vrow[lane * 2 + 1];
      const float4 u0 = vrow[128 + lane * 2], u1 = vrow[128 + lane * 2 + 1];
      float acc = a0.x * w0.x + a0.y * w0.y + a0.z * w0.z + a0.w * w0.w
                + a1.x * w1.x + a1.y * w1.y + a1.z * w1.z + a1.w * w1.w
                + b0.x * u0.x + b0.y * u0.y + b0.z * u0.z + b0.w * u0.w
                + b1.x * u1.x + b1.y * u1.y + b1.z * u1.z + b1.w * u1.w;
#pragma unroll
      for (int off = 32; off >= 1; off >>= 1) acc += __shfl_xor(acc, off);
      if (lane == 0) compat[t] = acc;
    }
  }
}

// ---------------- per-b: Gumbel argmax + log-softmax (one wave per b) ------
__global__ __launch_bounds__(256) void finalize_kernel(
    const float* __restrict__ compat, const int* __restrict__ neigh,
    const int* __restrict__ lengths, const int* __restrict__ cur,
    float* __restrict__ out) {
  const int b = blockIdx.x * 4 + (threadIdx.x >> 6);
  const int tid = threadIdx.x & 63;
  const int len = lengths[b];
  const bool valid = tid < NM;
  const float NEGMAX = -3.402823466e38f;
  float logit = NEGMAX;
  if (valid) {
    const float cm = compat[b * NM + tid] / 22.62741699796952f;  // / sqrt(512)
    logit = (tid < len) ? cm : -1e9f;
  }
  float z = NEGMAX;
  int zi = 1 << 20;
  if (valid) {
    // JAX partitionable threefry: counter = 64-bit flat index,
    // draw = out0 ^ out1 of threefry2x32(key=(0,1), (hi, lo)).
    const unsigned i_lo = (unsigned)b * 32u + (unsigned)tid;
    unsigned x0 = 0u;
    unsigned x1 = i_lo;
    threefry2x32(x0, x1);
    const unsigned bits = x0 ^ x1;
    const float fu = __uint_as_float((bits >> 9) | 0x3f800000u) - 1.0f;
    const float uu = fmaxf(1e-8f, fu + 1e-8f);
    const float g = -logf(-logf(uu));
    z = logit + g;
    zi = tid;
  }
#pragma unroll
  for (int off = 32; off >= 1; off >>= 1) {
    const float oz = __shfl_xor(z, off);
    const int oi = __shfl_xor(zi, off);
    if (oz > z || (oz == z && oi < zi)) { z = oz; zi = oi; }
  }
  float ml = logit;
#pragma unroll
  for (int off = 32; off >= 1; off >>= 1) ml = fmaxf(ml, __shfl_xor(ml, off));
  float ex = valid ? expf(logit - ml) : 0.f;
#pragma unroll
  for (int off = 32; off >= 1; off >>= 1) ex += __shfl_xor(ex, off);
  const float lsel = __shfl(logit, zi);
  if (tid == 0) {
    float lp = lsel - ml - logf(ex);
    int act = neigh[b * NM + zi];
    if (len <= 0) { act = cur[b]; lp = 0.f; }
    out[b] = (float)act;
    out[NBATCH + b] = lp;
  }
}

extern "C" void kernel_launch(void* const* d_in, const int* in_sizes, int n_in,
                              void* d_out, int out_size, void* d_ws, size_t ws_size,
                              hipStream_t stream) {
  const float* hs = (const float*)d_in[0];
  const float* hd = (const float*)d_in[1];
  const float* Ws = (const float*)d_in[2];
  const float* Wd = (const float*)d_in[3];
  const float* Wq = (const float*)d_in[4];
  const int* cur = (const int*)d_in[6];
  const int* neigh = (const int*)d_in[7];
  const int* lens = (const int*)d_in[8];
  float* out = (float*)d_out;

  char* ws = (char*)d_ws;
  size_t off = 0;
  int* cnt = (int*)(ws + off);        off += (size_t)NNODE * 4;        // 256 KB
  int* ovf_cnt = (int*)(ws + off);    off += 256;                      // pad
  int* bucket = (int*)(ws + off);     off += (size_t)NNODE * CAP * 4;  // 4 MB
  int* ovf_list = (int*)(ws + off);   off += (size_t)NBATCH * NM * 4;  // 512 KB
  float* compat = (float*)(ws + off); off += (size_t)NBATCH * NM * 4;  // 512 KB
  float* M2T = (float*)(ws + off);    off += (size_t)1024 * 512 * 4;       // 2 MB
  float* V = (float*)(ws + off);      off += (size_t)NBATCH * 2 * HDIM * 4; // 16 MB

  hipLaunchKernelGGL(zero_cnt, dim3(64), dim3(256), 0, stream, cnt, ovf_cnt);
  hipLaunchKernelGGL(b1_and_index, dim3(128 + NBATCH * NM / 256), dim3(256), 0, stream,
                     Ws, Wd, Wq, M2T, neigh, lens, cnt, bucket, ovf_cnt, ovf_list);
  hipLaunchKernelGGL(gemm_v, dim3(1024), dim3(256), 0, stream, hs, hd, cur, M2T, V);
  hipLaunchKernelGGL(stream_compat, dim3(NNODE / 4), dim3(256), 0, stream,
                     hs, hd, V, cnt, bucket, ovf_cnt, ovf_list, neigh, compat);
  hipLaunchKernelGGL(finalize_kernel, dim3(NBATCH / 4), dim3(256), 0, stream,
                     compat, neigh, lens, cur, out);
}

// Round 10
// 166.101 us; speedup vs baseline: 1.1175x; 1.0050x over previous
//
#include <hip/hip_runtime.h>
#include <cstdint>
#include <cstddef>

#define HDIM 512
#define NM 32
#define NBATCH 4096
#define NNODE 65536
#define CAP 16

typedef float v4f __attribute__((ext_vector_type(4)));

// ---------------- Threefry-2x32-20, key = (0,1)  (jax.random.key(1)) -------
__device__ __forceinline__ unsigned rotl32(unsigned x, unsigned d) {
  return (x << d) | (x >> (32u - d));
}

__device__ __forceinline__ void threefry2x32(unsigned& x0, unsigned& x1) {
  const unsigned ks0 = 0u, ks1 = 1u, ks2 = 0x1BD11BDBu; // 0^1^0x1BD11BDA
  x0 += ks0; x1 += ks1;
#define TF_RND(r) { x0 += x1; x1 = rotl32(x1, (r)); x1 ^= x0; }
  TF_RND(13) TF_RND(15) TF_RND(26) TF_RND(6)
  x0 += ks1; x1 += ks2 + 1u;
  TF_RND(17) TF_RND(29) TF_RND(16) TF_RND(24)
  x0 += ks2; x1 += ks0 + 2u;
  TF_RND(13) TF_RND(15) TF_RND(26) TF_RND(6)
  x0 += ks0; x1 += ks1 + 3u;
  TF_RND(17) TF_RND(29) TF_RND(16) TF_RND(24)
  x0 += ks1; x1 += ks2 + 4u;
  TF_RND(13) TF_RND(15) TF_RND(26) TF_RND(6)
  x0 += ks2; x1 += ks0 + 5u;
#undef TF_RND
}

// ---------------- zero cnt + ovf_cnt ---------------------------------------
__global__ __launch_bounds__(256) void zero_cnt(int* __restrict__ cnt,
                                                int* __restrict__ ovf_cnt) {
  const int t = blockIdx.x * 256 + threadIdx.x;   // 64 blocks -> 16384 int4
  ((int4*)cnt)[t] = make_int4(0, 0, 0, 0);
  if (t == 0) *ovf_cnt = 0;
}

// ---------------- fused: gemm_b1 (blocks 0..127) + build_index (128..639) --
__global__ __launch_bounds__(256) void b1_and_index(
    const float* __restrict__ Ws, const float* __restrict__ Wd,
    const float* __restrict__ Wq, float* __restrict__ M2T,
    const int* __restrict__ neigh, const int* __restrict__ lens,
    int* __restrict__ cnt, int* __restrict__ bucket,
    int* __restrict__ ovf_cnt, int* __restrict__ ovf_list) {
  constexpr int BK = 16, LDT = 68;  // 64 + 4 pad
  __shared__ float Ast[BK][LDT];
  __shared__ float Bst[BK][LDT];
  const int bid = blockIdx.x;
  const int tid = threadIdx.x;
  if (bid >= 128) {
    // ---- build_index part ----
    const int t = (bid - 128) * 256 + tid;   // t in [0, B*M)
    const int b = t >> 5, m = t & 31;
    if (m < lens[b]) {
      const int n = neigh[t];
      const int slot = atomicAdd(&cnt[n], 1);
      if (slot < CAP) bucket[n * CAP + slot] = t;
      else { const int o = atomicAdd(ovf_cnt, 1); ovf_list[o] = t; }
    }
    return;
  }
  // ---- gemm_b1 part ----
  const int row0 = (bid >> 3) * 64;      // combined c row (16 row-tiles)
  const int col0 = (bid & 7) * 64;       // e (8 col-tiles)
  const float* Abase = (row0 < 512) ? Ws : Wd;
  const int arow0 = (row0 < 512) ? row0 : row0 - 512;
  const int tx = tid & 15, ty = tid >> 4;
  const int lr = tid >> 2, lc = (tid & 3) * 4;
  float acc[4][4] = {};
  for (int k0 = 0; k0 < 512; k0 += BK) {
    float4 va = *(const float4*)(Abase + (size_t)(arow0 + lr) * 1536 + k0 + lc);
    float4 vb = *(const float4*)(Wq + (size_t)(col0 + lr) * 512 + k0 + lc);
    Ast[lc + 0][lr] = va.x; Ast[lc + 1][lr] = va.y;
    Ast[lc + 2][lr] = va.z; Ast[lc + 3][lr] = va.w;
    Bst[lc + 0][lr] = vb.x; Bst[lc + 1][lr] = vb.y;
    Bst[lc + 2][lr] = vb.z; Bst[lc + 3][lr] = vb.w;
    __syncthreads();
#pragma unroll
    for (int k = 0; k < BK; ++k) {
      float4 a4 = *(const float4*)&Ast[k][ty * 4];
      float4 b4 = *(const float4*)&Bst[k][tx * 4];
      float a[4] = {a4.x, a4.y, a4.z, a4.w};
      float bb[4] = {b4.x, b4.y, b4.z, b4.w};
#pragma unroll
      for (int i = 0; i < 4; ++i)
#pragma unroll
        for (int j = 0; j < 4; ++j) acc[i][j] += a[i] * bb[j];
    }
    __syncthreads();
  }
#pragma unroll
  for (int i = 0; i < 4; ++i) {
    float4 o;
    o.x = acc[i][0]; o.y = acc[i][1]; o.z = acc[i][2]; o.w = acc[i][3];
    *(float4*)(M2T + (size_t)(row0 + ty * 4 + i) * 512 + col0 + tx * 4) = o;
  }
}

// ---------------- V[b,c] = dot(hs[cur[b]]+hd[cur[b]], M2T[c,:]) ------------
// 256x64 tile, 8x8 micro (1 B of LDS per FLOP-pair -> 2.1 GB total LDS read,
// half of the 4x4 micro's 4.3 GB which was the measured ~62us LDS-BW wall).
// Register-prefetch + double LDS buffer, single barrier/iter (safe: writes of
// iter t+1 target buffer !cb(t); all waves passed sync(t) => done compute(t-1)).
// Per-output k-ascending FMA chain unchanged -> V bit-identical.
__global__ __launch_bounds__(256) void gemm_v(const float* __restrict__ hs,
                                              const float* __restrict__ hd,
                                              const int* __restrict__ cur,
                                              const float* __restrict__ Bm,
                                              float* __restrict__ C) {
  constexpr int BK = 16, LDTA = 260, LDTB = 68;   // 256+4, 64+4 pad
  __shared__ float Ast[2][BK][LDTA];              // 33.3 KB
  __shared__ float Bst[2][BK][LDTB];              //  8.7 KB
  const int tid = threadIdx.x;
  const int swz = (blockIdx.x & 7) * 32 + (blockIdx.x >> 3);  // 256 % 8 == 0
  const int row0 = (swz >> 4) * 256;     // 16 row-tiles of 256 b-rows
  const int col0 = (swz & 15) * 64;      // 16 col-tiles of 64 c-cols
  const int tx = tid & 7, ty = tid >> 3; // 8 x 32 thread grid, 8x8 micro
  const int ar = tid >> 2;               // 0..63
  const int af = (tid & 3) * 4;          // k-float offset 0,4,8,12

  size_t na[4];
#pragma unroll
  for (int q = 0; q < 4; ++q)
    na[q] = (size_t)cur[row0 + ar + 64 * q] * HDIM + af;
  const float* bp = Bm + (size_t)(col0 + ar) * 512 + af;

  float4 sa[4], sd[4], vb;
#pragma unroll
  for (int q = 0; q < 4; ++q) {
    sa[q] = *(const float4*)(hs + na[q]);
    sd[q] = *(const float4*)(hd + na[q]);
  }
  vb = *(const float4*)(bp);

  float acc[8][8] = {};
  int cb = 0;
#pragma unroll 1
  for (int t = 0; t < 32; ++t) {
#pragma unroll
    for (int q = 0; q < 4; ++q) {
      Ast[cb][af + 0][ar + 64 * q] = sa[q].x + sd[q].x;
      Ast[cb][af + 1][ar + 64 * q] = sa[q].y + sd[q].y;
      Ast[cb][af + 2][ar + 64 * q] = sa[q].z + sd[q].z;
      Ast[cb][af + 3][ar + 64 * q] = sa[q].w + sd[q].w;
    }
    Bst[cb][af + 0][ar] = vb.x;
    Bst[cb][af + 1][ar] = vb.y;
    Bst[cb][af + 2][ar] = vb.z;
    Bst[cb][af + 3][ar] = vb.w;
    __syncthreads();
    if (t < 31) {
      const int k0 = (t + 1) * BK;
#pragma unroll
      for (int q = 0; q < 4; ++q) {
        sa[q] = *(const float4*)(hs + na[q] + k0);
        sd[q] = *(const float4*)(hd + na[q] + k0);
      }
      vb = *(const float4*)(bp + k0);
    }
#pragma unroll
    for (int k = 0; k < BK; ++k) {
      const float4 a0 = *(const float4*)&Ast[cb][k][ty * 8];
      const float4 a1 = *(const float4*)&Ast[cb][k][ty * 8 + 4];
      const float4 b0 = *(const float4*)&Bst[cb][k][tx * 8];
      const float4 b1 = *(const float4*)&Bst[cb][k][tx * 8 + 4];
      const float a[8] = {a0.x, a0.y, a0.z, a0.w, a1.x, a1.y, a1.z, a1.w};
      const float bb[8] = {b0.x, b0.y, b0.z, b0.w, b1.x, b1.y, b1.z, b1.w};
#pragma unroll
      for (int i = 0; i < 8; ++i)
#pragma unroll
        for (int j = 0; j < 8; ++j) acc[i][j] += a[i] * bb[j];
    }
    cb ^= 1;
  }
#pragma unroll
  for (int i = 0; i < 8; ++i) {
    float* cp = C + (size_t)(row0 + ty * 8 + i) * 1024 + col0 + tx * 8;
    float4 o0, o1;
    o0.x = acc[i][0]; o0.y = acc[i][1]; o0.z = acc[i][2]; o0.w = acc[i][3];
    o1.x = acc[i][4]; o1.y = acc[i][5]; o1.z = acc[i][6]; o1.w = acc[i][7];
    *(float4*)cp = o0;
    *(float4*)(cp + 4) = o1;
  }
}

// ---------------- streaming compat: one wave per node + ovf drain ----------
__global__ __launch_bounds__(256) void stream_compat(
    const float* __restrict__ hs, const float* __restrict__ hd,
    const float* __restrict__ V, const int* __restrict__ cnt,
    const int* __restrict__ bucket, const int* __restrict__ ovf_cnt,
    const int* __restrict__ ovf_list, const int* __restrict__ neigh,
    float* __restrict__ compat) {
  const int n = blockIdx.x * 4 + (threadIdx.x >> 6);   // node per wave
  const int lane = threadIdx.x & 63;
  const int c = cnt[n];
  if (c != 0) {
    const v4f* a4 = (const v4f*)(hs + (size_t)n * HDIM);
    const v4f* c4 = (const v4f*)(hd + (size_t)n * HDIM);
    const v4f a0 = __builtin_nontemporal_load(a4 + lane * 2);
    const v4f a1 = __builtin_nontemporal_load(a4 + lane * 2 + 1);
    const v4f b0 = __builtin_nontemporal_load(c4 + lane * 2);
    const v4f b1 = __builtin_nontemporal_load(c4 + lane * 2 + 1);
    const int cc = (c < CAP) ? c : CAP;
    for (int e = 0; e < cc; ++e) {
      const int t = bucket[n * CAP + e];
      const int b = t >> 5;
      const float4* vrow = (const float4*)(V + (size_t)b * (2 * HDIM));
      const float4 w0 = vrow[lane * 2], w1 = vrow[lane * 2 + 1];
      const float4 u0 = vrow[128 + lane * 2], u1 = vrow[128 + lane * 2 + 1];
      float acc = a0.x * w0.x + a0.y * w0.y + a0.z * w0.z + a0.w * w0.w
                + a1.x * w1.x + a1.y * w1.y + a1.z * w1.z + a1.w * w1.w
                + b0.x * u0.x + b0.y * u0.y + b0.z * u0.z + b0.w * u0.w
                + b1.x * u1.x + b1.y * u1.y + b1.z * u1.z + b1.w * u1.w;
#pragma unroll
      for (int off = 32; off >= 1; off >>= 1) acc += __shfl_xor(acc, off);
      if (lane == 0) compat[t] = acc;
    }
  }
  // overflow drain (ovf is ~always empty; disjoint t-set -> no race)
  if (blockIdx.x < 32) {
    const int nw = *ovf_cnt;
    for (int e = blockIdx.x * 4 + (threadIdx.x >> 6); e < nw; e += 128) {
      const int t = ovf_list[e];
      const int b = t >> 5;
      const int nn = neigh[t];
      const float4* a4 = (const float4*)(hs + (size_t)nn * HDIM);
      const float4* c4 = (const float4*)(hd + (size_t)nn * HDIM);
      const float4 a0 = a4[lane * 2], a1 = a4[lane * 2 + 1];
      const float4 b0 = c4[lane * 2], b1 = c4[lane * 2 + 1];
      const float4* vrow = (const float4*)(V + (size_t)b * (2 * HDIM));
      const float4 w0 = vrow[lane * 2], w1 = vrow[lane * 2 + 1];
      const float4 u0 = vrow[128 + lane * 2], u1 = vrow[128 + lane * 2 + 1];
      float acc = a0.x * w0.x + a0.y * w0.y + a0.z * w0.z + a0.w * w0.w
                + a1.x * w1.x + a1.y * w1.y + a1.z * w1.z + a1.w * w1.w
                + b0.x * u0.x + b0.y * u0.y + b0.z * u0.z + b0.w * u0.w
                + b1.x * u1.x + b1.y * u1.y + b1.z * u1.z + b1.w * u1.w;
#pragma unroll
      for (int off = 32; off >= 1; off >>= 1) acc += __shfl_xor(acc, off);
      if (lane == 0) compat[t] = acc;
    }
  }
}

// ---------------- per-b: Gumbel argmax + log-softmax (one wave per b) ------
__global__ __launch_bounds__(256) void finalize_kernel(
    const float* __restrict__ compat, const int* __restrict__ neigh,
    const int* __restrict__ lengths, const int* __restrict__ cur,
    float* __restrict__ out) {
  const int b = blockIdx.x * 4 + (threadIdx.x >> 6);
  const int tid = threadIdx.x & 63;
  const int len = lengths[b];
  const bool valid = tid < NM;
  const float NEGMAX = -3.402823466e38f;
  float logit = NEGMAX;
  if (valid) {
    const float cm = compat[b * NM + tid] / 22.62741699796952f;  // / sqrt(512)
    logit = (tid < len) ? cm : -1e9f;
  }
  float z = NEGMAX;
  int zi = 1 << 20;
  if (valid) {
    // JAX partitionable threefry: counter = 64-bit flat index,
    // draw = out0 ^ out1 of threefry2x32(key=(0,1), (hi, lo)).
    const unsigned i_lo = (unsigned)b * 32u + (unsigned)tid;
    unsigned x0 = 0u;
    unsigned x1 = i_lo;
    threefry2x32(x0, x1);
    const unsigned bits = x0 ^ x1;
    const float fu = __uint_as_float((bits >> 9) | 0x3f800000u) - 1.0f;
    const float uu = fmaxf(1e-8f, fu + 1e-8f);
    const float g = -logf(-logf(uu));
    z = logit + g;
    zi = tid;
  }
#pragma unroll
  for (int off = 32; off >= 1; off >>= 1) {
    const float oz = __shfl_xor(z, off);
    const int oi = __shfl_xor(zi, off);
    if (oz > z || (oz == z && oi < zi)) { z = oz; zi = oi; }
  }
  float ml = logit;
#pragma unroll
  for (int off = 32; off >= 1; off >>= 1) ml = fmaxf(ml, __shfl_xor(ml, off));
  float ex = valid ? expf(logit - ml) : 0.f;
#pragma unroll
  for (int off = 32; off >= 1; off >>= 1) ex += __shfl_xor(ex, off);
  const float lsel = __shfl(logit, zi);
  if (tid == 0) {
    float lp = lsel - ml - logf(ex);
    int act = neigh[b * NM + zi];
    if (len <= 0) { act = cur[b]; lp = 0.f; }
    out[b] = (float)act;
    out[NBATCH + b] = lp;
  }
}

extern "C" void kernel_launch(void* const* d_in, const int* in_sizes, int n_in,
                              void* d_out, int out_size, void* d_ws, size_t ws_size,
                              hipStream_t stream) {
  const float* hs = (const float*)d_in[0];
  const float* hd = (const float*)d_in[1];
  const float* Ws = (const float*)d_in[2];
  const float* Wd = (const float*)d_in[3];
  const float* Wq = (const float*)d_in[4];
  const int* cur = (const int*)d_in[6];
  const int* neigh = (const int*)d_in[7];
  const int* lens = (const int*)d_in[8];
  float* out = (float*)d_out;

  char* ws = (char*)d_ws;
  size_t off = 0;
  int* cnt = (int*)(ws + off);        off += (size_t)NNODE * 4;        // 256 KB
  int* ovf_cnt = (int*)(ws + off);    off += 256;                      // pad
  int* bucket = (int*)(ws + off);     off += (size_t)NNODE * CAP * 4;  // 4 MB
  int* ovf_list = (int*)(ws + off);   off += (size_t)NBATCH * NM * 4;  // 512 KB
  float* compat = (float*)(ws + off); off += (size_t)NBATCH * NM * 4;  // 512 KB
  float* M2T = (float*)(ws + off);    off += (size_t)1024 * 512 * 4;       // 2 MB
  float* V = (float*)(ws + off);      off += (size_t)NBATCH * 2 * HDIM * 4; // 16 MB

  hipLaunchKernelGGL(zero_cnt, dim3(64), dim3(256), 0, stream, cnt, ovf_cnt);
  hipLaunchKernelGGL(b1_and_index, dim3(128 + NBATCH * NM / 256), dim3(256), 0, stream,
                     Ws, Wd, Wq, M2T, neigh, lens, cnt, bucket, ovf_cnt, ovf_list);
  hipLaunchKernelGGL(gemm_v, dim3(256), dim3(256), 0, stream, hs, hd, cur, M2T, V);
  hipLaunchKernelGGL(stream_compat, dim3(NNODE / 4), dim3(256), 0, stream,
                     hs, hd, V, cnt, bucket, ovf_cnt, ovf_list, neigh, compat);
  hipLaunchKernelGGL(finalize_kernel, dim3(NBATCH / 4), dim3(256), 0, stream,
                     compat, neigh, lens, cur, out);
}